// Round 13
// baseline (639.706 us; speedup 1.0000x reference)
//
#include <hip/hip_runtime.h>

typedef unsigned short u16;
typedef unsigned int   u32;
typedef float  f32x4  __attribute__((ext_vector_type(4)));
typedef u32    u32x4  __attribute__((ext_vector_type(4)));
typedef __bf16 bf16x8 __attribute__((ext_vector_type(8)));

#define DEV __device__ __forceinline__

DEV float b2f(u16 u){ return __uint_as_float(((u32)u) << 16); }
DEV u16 f2b(float f){
  u32 u = __float_as_uint(f);
  u32 r = 0x7FFFu + ((u >> 16) & 1u);
  return (u16)((u + r) >> 16);
}
DEV u32 pack2(float a, float b){ return (u32)f2b(a) | ((u32)f2b(b) << 16); }
DEV uint4 pack8(const float* o){
  uint4 r;
  r.x = pack2(o[0], o[1]); r.y = pack2(o[2], o[3]);
  r.z = pack2(o[4], o[5]); r.w = pack2(o[6], o[7]);
  return r;
}

// D = A(16x32)*B(32x16)+C. A/B frag: lane holds 8 contiguous k
// (k = 8*(lane>>4)+e) of row/col (lane&15). C/D: col=lane&15,
// row=4*(lane>>4)+reg  [m89/m91-verified].
DEV f32x4 mfma16(u32x4 a, u32x4 b, f32x4 c){
  return __builtin_amdgcn_mfma_f32_16x16x32_bf16(
      __builtin_bit_cast(bf16x8, a), __builtin_bit_cast(bf16x8, b), c, 0, 0, 0);
}

DEV void gload16(const u16* g, u16* l){
  __builtin_amdgcn_global_load_lds((const __attribute__((address_space(1))) void*)(g),
                                   (__attribute__((address_space(3))) void*)(l), 16, 0, 0);
}

// ---------------------------------------------------------------- transposes
// 3 x [512][512] f32 -> bf16 transposed (QKV weights), batched via blockIdx.z
__global__ __launch_bounds__(256) void tranb3(
    const float* __restrict__ sA, const float* __restrict__ sB,
    const float* __restrict__ sC,
    u16* __restrict__ dA, u16* __restrict__ dB, u16* __restrict__ dC){
  __shared__ float tile[32][33];
  const float* src = (blockIdx.z == 0) ? sA : (blockIdx.z == 1) ? sB : sC;
  u16* dst = (blockIdx.z == 0) ? dA : (blockIdx.z == 1) ? dB : dC;
  const int bx = blockIdx.x * 32, by = blockIdx.y * 32;
  const int tx = threadIdx.x, ty = threadIdx.y;
#pragma unroll
  for (int i = 0; i < 4; ++i)
    tile[ty + i * 8][tx] = src[(size_t)(by + ty + i * 8) * 512 + bx + tx];
  __syncthreads();
#pragma unroll
  for (int i = 0; i < 4; ++i)
    dst[(size_t)(bx + ty + i * 8) * 512 + by + tx] = f2b(tile[tx][ty + i * 8]);
}

// [512][512] f32 -> dst[c*1024 + off + r] (fused projT, ld=1024, col offset)
__global__ __launch_bounds__(256) void tranbP(const float* __restrict__ src,
                                              u16* __restrict__ dst, int off){
  __shared__ float tile[32][33];
  const int bx = blockIdx.x * 32, by = blockIdx.y * 32;
  const int tx = threadIdx.x, ty = threadIdx.y;
#pragma unroll
  for (int i = 0; i < 4; ++i)
    tile[ty + i * 8][tx] = src[(size_t)(by + ty + i * 8) * 512 + bx + tx];
  __syncthreads();
#pragma unroll
  for (int i = 0; i < 4; ++i)
    dst[(size_t)(bx + ty + i * 8) * 1024 + off + by + tx] = f2b(tile[tx][ty + i * 8]);
}

// src [R][C] f32 -> dst [C][R] bf16 (FFN weights)
__global__ __launch_bounds__(256) void tranb(const float* __restrict__ src, u16* __restrict__ dst,
                                             int R, int C){
  __shared__ float tile[32][33];
  const int bx = blockIdx.x * 32, by = blockIdx.y * 32;
  const int tx = threadIdx.x, ty = threadIdx.y;
#pragma unroll
  for (int i = 0; i < 4; ++i)
    tile[ty + i * 8][tx] = src[(size_t)(by + ty + i * 8) * C + bx + tx];
  __syncthreads();
#pragma unroll
  for (int i = 0; i < 4; ++i)
    dst[(size_t)(bx + ty + i * 8) * R + by + tx] = f2b(tile[tx][ty + i * 8]);
}

// ---------------------------------------------------------------- layernorm
template<int TWO>
__global__ __launch_bounds__(256) void ln_k(const float* __restrict__ x,
    const float* __restrict__ g1, const float* __restrict__ b1,
    const float* __restrict__ g2, const float* __restrict__ b2,
    u16* __restrict__ y1, u16* __restrict__ y2){
  const int tid = threadIdx.x, lane = tid & 63, wv = tid >> 6;
  const size_t row  = (size_t)blockIdx.x * 4 + wv;
  const size_t boff = row * 512 + lane * 8;
  float f[8];
  {
    const f32x4* p = (const f32x4*)(x + boff);
    const f32x4 a = p[0], b = p[1];
#pragma unroll
    for (int j = 0; j < 4; ++j){ f[j] = a[j]; f[4 + j] = b[j]; }
  }
  float s1 = 0.f, s2 = 0.f;
#pragma unroll
  for (int j = 0; j < 8; ++j){ s1 += f[j]; s2 += f[j] * f[j]; }
#pragma unroll
  for (int off = 32; off > 0; off >>= 1){
    s1 += __shfl_xor(s1, off);
    s2 += __shfl_xor(s2, off);
  }
  const float m   = s1 * (1.0f / 512.0f);
  const float var = s2 * (1.0f / 512.0f) - m * m;
  const float inv = rsqrtf(var + 1e-4f);
  const int cb = lane * 8;
  float o[8];
#pragma unroll
  for (int j = 0; j < 8; ++j) o[j] = (f[j] - m) * inv * g1[cb + j] + b1[cb + j];
  *(uint4*)(y1 + boff) = pack8(o);
  if (TWO){
#pragma unroll
    for (int j = 0; j < 8; ++j) o[j] = (f[j] - m) * inv * g2[cb + j] + b2[cb + j];
    *(uint4*)(y2 + boff) = pack8(o);
  }
}

// ---------------------------------------------------------------- GEMM 256x256
// out = [A | A2nd](switch at K-step nkA, BK=32 steps) @ Bt[N][K](ldb)^T + bias
// EPI 0: bf16 | 1: bf16+gelu | 2: f32 + opt 2nd bias (b1p) + f32 res;
//   EPI2 b0p may be null (accumulate pass). FUSE3: segmented bias + split
//   512-stride outputs.
// DEEP PIPELINE (derived, ledger-verified):
//   3 rotating LDS slots (32KB = A[256][32] + B[256][32]), stage 2 K-steps
//   ahead. 2 phases per K-step (16 MFMA each: M-half quadrant). Per phase:
//   {ds_read issue, stage issue} -> s_barrier -> lgkmcnt(0) -> MFMA.
//   vmcnt(4) once per K-step (end P2), never 0 until tail. Slot overwrite
//   is >= 2 phases after last read, with all-wave read-completion forced by
//   the lgkm0-before-next-barrier chain. 8 waves, wave tile 128x64.
template<int EPI, bool FUSE3>
__global__ __launch_bounds__(512, 2) void gemm256(const u16* __restrict__ A,
    const u16* __restrict__ A2nd, int nkA,
    const u16* __restrict__ Bt, int ldb,
    const float* __restrict__ b0p, const float* __restrict__ b1p,
    const float* __restrict__ b2p,
    const float* __restrict__ res,
    void* __restrict__ out0, void* __restrict__ out1, void* __restrict__ out2,
    int Nd, int K, int lda){
  __shared__ __align__(16) u16 smem[65536];   // 128KB: 3x32KB staging; epilogue reuse
  const int tid  = threadIdx.x;
  const int lane = tid & 63;
  const int lr = lane & 15, lg = lane >> 4;   // lg in 0..3 (k-chunk of 8)
  const int wave = tid >> 6;
  const int wm = (wave >> 2) * 128, wn = (wave & 3) * 64;
  // T1: bijective XCD swizzle (all grids have nwg % 8 == 0)
  const u32 fd  = blockIdx.y * gridDim.x + blockIdx.x;
  const u32 cpx = (gridDim.x * gridDim.y) >> 3;
  const u32 T   = (fd & 7) * cpx + (fd >> 3);
  const int m0 = (T / gridDim.x) * 256, n0 = (T % gridDim.x) * 256;
  const int nk = K >> 5;                      // BK=32 K-steps

  f32x4 acc[8][4] = {};

  // slot s = t%3 at s*16384 u16: A [256][32] (8192), B at +8192.
  // LDS chunk (r, c) holds global chunk (r, c ^ ((r>>1)&3)).
  auto stageA = [&](int t){
    const u16* Ap; int kb;
    if (t < nkA){ Ap = A;    kb = t * 32; }
    else        { Ap = A2nd; kb = (t - nkA) * 32; }
    const int so = (t % 3) * 16384;
#pragma unroll
    for (int i = 0; i < 2; ++i){
      const int c = i * 512 + tid;
      const int r = c >> 2, gc = (c & 3) ^ ((r >> 1) & 3);
      gload16(Ap + (size_t)(m0 + r) * lda + kb + gc * 8, smem + so + c * 8);
    }
  };
  auto stageB = [&](int t){
    const int so = (t % 3) * 16384 + 8192;
    const int kb = t * 32;
#pragma unroll
    for (int i = 0; i < 2; ++i){
      const int c = i * 512 + tid;
      const int r = c >> 2, gc = (c & 3) ^ ((r >> 1) & 3);
      gload16(Bt + (size_t)(n0 + r) * ldb + kb + gc * 8, smem + so + c * 8);
    }
  };

  // prologue: B(0),A(0),B(1),A(1) in flight; drain first K-step.
  stageB(0); stageA(0); stageB(1); stageA(1);
  asm volatile("s_waitcnt vmcnt(4)" ::: "memory");
  __builtin_amdgcn_s_barrier();

  for (int t = 0; t < nk; ++t){
    const int so = (t % 3) * 16384;
    u32x4 af[4], bf[4];
    // ---- P1: reads (bf all + af mh0), stage B(t+2), barrier, MFMA ----
#pragma unroll
    for (int nt = 0; nt < 4; ++nt){
      const int row = wn + nt * 16 + lr;
      bf[nt] = *(const u32x4*)&smem[so + 8192 + row * 32 + ((lg ^ ((row >> 1) & 3)) << 3)];
    }
#pragma unroll
    for (int mt = 0; mt < 4; ++mt){
      const int row = wm + mt * 16 + lr;
      af[mt] = *(const u32x4*)&smem[so + row * 32 + ((lg ^ ((row >> 1) & 3)) << 3)];
    }
    if (t + 2 < nk) stageB(t + 2);
    __builtin_amdgcn_s_barrier();
    asm volatile("s_waitcnt lgkmcnt(0)" ::: "memory");
    __builtin_amdgcn_sched_barrier(0);
    __builtin_amdgcn_s_setprio(1);
#pragma unroll
    for (int mt = 0; mt < 4; ++mt)
#pragma unroll
      for (int nt = 0; nt < 4; ++nt)
        acc[mt][nt] = mfma16(af[mt], bf[nt], acc[mt][nt]);
    __builtin_amdgcn_s_setprio(0);
    __builtin_amdgcn_sched_barrier(0);
    // ---- P2: reads (af mh1), stage A(t+2), vmcnt, barrier, MFMA ----
#pragma unroll
    for (int mt = 0; mt < 4; ++mt){
      const int row = wm + 64 + mt * 16 + lr;
      af[mt] = *(const u32x4*)&smem[so + row * 32 + ((lg ^ ((row >> 1) & 3)) << 3)];
    }
    if (t + 2 < nk){
      stageA(t + 2);
      asm volatile("s_waitcnt vmcnt(4)" ::: "memory");  // next K-step resident
    } else if (t + 1 < nk){
      asm volatile("s_waitcnt vmcnt(0)" ::: "memory");
    }
    __builtin_amdgcn_s_barrier();
    asm volatile("s_waitcnt lgkmcnt(0)" ::: "memory");
    __builtin_amdgcn_sched_barrier(0);
    __builtin_amdgcn_s_setprio(1);
#pragma unroll
    for (int mt = 0; mt < 4; ++mt)
#pragma unroll
      for (int nt = 0; nt < 4; ++nt)
        acc[4 + mt][nt] = mfma16(af[mt], bf[nt], acc[4 + mt][nt]);
    __builtin_amdgcn_s_setprio(0);
    __builtin_amdgcn_sched_barrier(0);
  }
  __syncthreads();                            // smem reuse for epilogue

  if (EPI == 2){
    // f32 out + f32 res: two half-passes of 128 rows (128x256 f32 = 128KB)
    float* Cf = (float*)smem;
    float* o = (float*)out0;
#pragma unroll
    for (int h = 0; h < 2; ++h){
      if ((wave >> 2) == h){
#pragma unroll
        for (int m = 0; m < 8; ++m)
#pragma unroll
          for (int nt = 0; nt < 4; ++nt){
            const int col = wn + nt * 16 + lr;
            float bv = b0p ? b0p[n0 + col] : 0.0f;
            if (b1p) bv += b1p[n0 + col];
#pragma unroll
            for (int r = 0; r < 4; ++r)
              Cf[(m * 16 + lg * 4 + r) * 256 + col] = acc[m][nt][r] + bv;
          }
      }
      __syncthreads();
#pragma unroll
      for (int p = 0; p < 16; ++p){
        const int rr = p * 8 + (tid >> 6);
        const int cc = (tid & 63) * 4;
        f32x4 c = *(f32x4*)&Cf[rr * 256 + cc];
        const size_t gi = (size_t)(m0 + h * 128 + rr) * Nd + n0 + cc;
        c += *(const f32x4*)(res + gi);
        *(f32x4*)(o + gi) = c;
      }
      __syncthreads();
    }
  } else {
    // bf16 out: stage full 256x256 u16 tile (128KB), coalesced stores
    u16* Cl = smem;
#pragma unroll
    for (int m = 0; m < 8; ++m)
#pragma unroll
      for (int nt = 0; nt < 4; ++nt){
        const int col = n0 + wn + nt * 16 + lr;
        float bv;
        if (FUSE3){
          if (col >= 1024)      bv = b2p[col - 1024];
          else if (col >= 512)  bv = b1p[col - 512];
          else                  bv = b0p[col];
        } else bv = b0p[col];
#pragma unroll
        for (int r = 0; r < 4; ++r){
          float v2 = acc[m][nt][r] + bv;
          if (EPI == 1) v2 = 0.5f * v2 * (1.0f + erff(v2 * 0.70710678118654752f));
          Cl[(wm + m * 16 + lg * 4 + r) * 256 + wn + nt * 16 + lr] = f2b(v2);
        }
      }
    __syncthreads();
    u16* o = (u16*)out0;
    int ncol = n0;
    if (FUSE3){
      const int grp = n0 >> 9;
      o = (u16*)(grp == 0 ? out0 : grp == 1 ? out1 : out2);
      ncol = n0 & 511;
    }
#pragma unroll
    for (int p = 0; p < 16; ++p){
      const int rr = p * 16 + (tid >> 5);
      const int cc = (tid & 31) * 8;
      *(uint4*)(o + (size_t)(m0 + rr) * (FUSE3 ? 512 : Nd) + ncol + cc) =
          *(uint4*)&Cl[rr * 256 + cc];
    }
  }
}

// ---------------------------------------------------------------- attention
// One block per (sequence, head). T=64, hd=64, 4 waves. Writes output
// IN-PLACE over q. Token t -> row base + t*tstr.
__global__ __launch_bounds__(256, 2) void attn64(u16* __restrict__ q,
    const u16* __restrict__ k, const u16* __restrict__ v,
    const float* __restrict__ relw,
    int sscale, int tstr){
  __shared__ __align__(16) u16 Qs[64 * 80];
  __shared__ __align__(16) u16 Ks[64 * 80];
  __shared__ __align__(16) u16 Vt[64 * 80];   // V transposed: Vt[d][t]
  __shared__ __align__(16) u16 Ps[64 * 80];
  __shared__ float Ss[64 * 68];
  __shared__ float tb[128];

  const int s = blockIdx.x, head = blockIdx.y;
  const int tid = threadIdx.x;
  const int lane = tid & 63, wv = tid >> 6;
  const int lr = lane & 15, lg = lane >> 4;
  const int base = (s >> 6) * 4096 + (s & 63) * sscale;

  if (tid < 127) tb[tid] = relw[tid * 8 + head];

#pragma unroll
  for (int rep = 0; rep < 2; ++rep){
    const int e = rep * 2048 + tid * 8;
    const int t = e >> 6, c = e & 63;
    const size_t goff = (size_t)(base + t * tstr) * 512 + head * 64 + c;
    *(uint4*)&Qs[t * 80 + c] = *(const uint4*)(q + goff);
    *(uint4*)&Ks[t * 80 + c] = *(const uint4*)(k + goff);
    const uint4 vvv = *(const uint4*)(v + goff);
    u32 w;
    w = vvv.x; Vt[(c + 0) * 80 + t] = (u16)w; Vt[(c + 1) * 80 + t] = (u16)(w >> 16);
    w = vvv.y; Vt[(c + 2) * 80 + t] = (u16)w; Vt[(c + 3) * 80 + t] = (u16)(w >> 16);
    w = vvv.z; Vt[(c + 4) * 80 + t] = (u16)w; Vt[(c + 5) * 80 + t] = (u16)(w >> 16);
    w = vvv.w; Vt[(c + 6) * 80 + t] = (u16)w; Vt[(c + 7) * 80 + t] = (u16)(w >> 16);
  }
  __syncthreads();

  const int i0 = wv * 16;
  u32x4 af[2];
#pragma unroll
  for (int kk = 0; kk < 2; ++kk)
    af[kk] = *(const u32x4*)&Qs[(i0 + lr) * 80 + kk * 32 + lg * 8];
#pragma unroll
  for (int jt = 0; jt < 4; ++jt){
    f32x4 acc = {};
#pragma unroll
    for (int kk = 0; kk < 2; ++kk){
      const u32x4 bf = *(const u32x4*)&Ks[(jt * 16 + lr) * 80 + kk * 32 + lg * 8];
      acc = mfma16(af[kk], bf, acc);
    }
#pragma unroll
    for (int r = 0; r < 4; ++r){
      const int i = i0 + lg * 4 + r;
      const int j = jt * 16 + lr;
      Ss[i * 68 + j] = acc[r] * 0.125f + tb[j - i + 63];
    }
  }
  __syncthreads();

  {
    const int rr = tid >> 2, cp = tid & 3;
    float ev[16];
    float mx = -3.0e38f;
#pragma unroll
    for (int u = 0; u < 16; ++u){ ev[u] = Ss[rr * 68 + cp * 16 + u]; mx = fmaxf(mx, ev[u]); }
    mx = fmaxf(mx, __shfl_xor(mx, 1, 4));
    mx = fmaxf(mx, __shfl_xor(mx, 2, 4));
    float sum = 0.f;
#pragma unroll
    for (int u = 0; u < 16; ++u){ ev[u] = expf(ev[u] - mx); sum += ev[u]; }
    sum += __shfl_xor(sum, 1, 4);
    sum += __shfl_xor(sum, 2, 4);
    const float inv = 1.0f / sum;
#pragma unroll
    for (int u = 0; u < 16; ++u) Ps[rr * 80 + cp * 16 + u] = f2b(ev[u] * inv);
  }
  __syncthreads();

  u32x4 pa[2];
#pragma unroll
  for (int kk = 0; kk < 2; ++kk)
    pa[kk] = *(const u32x4*)&Ps[(i0 + lr) * 80 + kk * 32 + lg * 8];
#pragma unroll
  for (int dt = 0; dt < 4; ++dt){
    f32x4 acc = {};
#pragma unroll
    for (int kk = 0; kk < 2; ++kk){
      const u32x4 bf = *(const u32x4*)&Vt[(dt * 16 + lr) * 80 + kk * 32 + lg * 8];
      acc = mfma16(pa[kk], bf, acc);
    }
#pragma unroll
    for (int r = 0; r < 4; ++r)
      Qs[(i0 + lg * 4 + r) * 80 + dt * 16 + lr] = f2b(acc[r]);
  }
  __syncthreads();

#pragma unroll
  for (int p = 0; p < 2; ++p){
    const int rr = p * 32 + (tid >> 3);
    const int cc = (tid & 7) * 8;
    *(uint4*)(q + (size_t)(base + rr * tstr) * 512 + head * 64 + cc) =
        *(uint4*)&Qs[rr * 80 + cc];
  }
}

// ---------------------------------------------------------------- launcher
extern "C" void kernel_launch(void* const* d_in, const int* in_sizes, int n_in,
                              void* d_out, int out_size, void* d_ws, size_t ws_size,
                              hipStream_t stream){
  const float* x      = (const float*)d_in[0];
  const float* row_qw = (const float*)d_in[1];  const float* row_qb = (const float*)d_in[2];
  const float* row_kw = (const float*)d_in[3];  const float* row_kb = (const float*)d_in[4];
  const float* row_vw = (const float*)d_in[5];  const float* row_vb = (const float*)d_in[6];
  const float* row_pw = (const float*)d_in[7];  const float* row_pb = (const float*)d_in[8];
  const float* col_qw = (const float*)d_in[9];  const float* col_qb = (const float*)d_in[10];
  const float* col_kw = (const float*)d_in[11]; const float* col_kb = (const float*)d_in[12];
  const float* col_vw = (const float*)d_in[13]; const float* col_vb = (const float*)d_in[14];
  const float* col_pw = (const float*)d_in[15]; const float* col_pb = (const float*)d_in[16];
  const float* rg  = (const float*)d_in[17]; const float* rb  = (const float*)d_in[18];
  const float* cg  = (const float*)d_in[19]; const float* cb  = (const float*)d_in[20];
  const float* l2g = (const float*)d_in[21]; const float* l2b = (const float*)d_in[22];
  const float* ffw1 = (const float*)d_in[23]; const float* ffb1 = (const float*)d_in[24];
  const float* ffw2 = (const float*)d_in[25]; const float* ffb2 = (const float*)d_in[26];
  const float* rrel = (const float*)d_in[27]; const float* crel = (const float*)d_in[28];
  float* outp = (float*)d_out;
  u16* outp16 = (u16*)d_out;

  const size_t ACT = (size_t)32768 * 512;          // activation buffer (elems)
  const size_t W55 = (size_t)512 * 512;
  const size_t NEED = (4 * ACT + 8 * W55) * 2;     // bytes = 138,412,032
  if (ws_size < NEED) return;                      // sentinel: d_out stays 0

  u16* A0 = (u16*)d_ws;        // rowLN / ln2 out
  u16* A1 = A0 + ACT;          // rowQ -> rowO ; FFN hid (A1..A2, [32768][1024])
  u16* A2 = A1 + ACT;          // rowK ; colQ -> colO
  u16* A3 = A2 + ACT;          // rowV ; colK
  u16* D0 = outp16;            // colLN (bf16 scratch in d_out, dies at proj)
  u16* D1 = outp16 + ACT;      // colV  (bf16 scratch in d_out, dies at proj)
  u16* wtb = A3 + ACT;         // weight area: 8 x W55
  u16* wt_q = wtb;  u16* wt_k = wtb + W55;  u16* wt_v = wtb + 2 * W55;
  u16* wt_p = wtb + 3 * W55;   // fused projT [512][1024] = 2 slots (3..4)
  u16* f1t  = wtb;             // FF phase: [2048][512] = 4 slots (0..3)
  u16* f2t  = wtb + 4 * W55;   // FF phase: [512][2048] = 4 slots (4..7)
  u16* hid  = A1;              // [32768][1024] bf16 = A1..A2

  const dim3 tpb(32, 8);
  const dim3 gQKV(6, 128);     // 256^2 tiles: N=1536 -> 768 blocks (%8==0)
  const dim3 gProj(2, 128);    // 256 blocks
  const dim3 gFF1(4, 128);     // 512 blocks
  const dim3 gFF2(2, 128);     // 256 blocks
  const dim3 gAttn(512, 8);

  // ---- prologue: both LNs in one pass (x read once) ----
  ln_k<1><<<8192, 256, 0, stream>>>(x, rg, rb, cg, cb, A0, D0);

  // ---- row branch ----
  tranb3<<<dim3(16, 16, 3), tpb, 0, stream>>>(row_qw, row_kw, row_vw, wt_q, wt_k, wt_v);
  tranbP<<<dim3(16, 16), tpb, 0, stream>>>(row_pw, wt_p, 0);
  gemm256<0, true><<<gQKV, 512, 0, stream>>>(A0, A0, 999, wt_q, 512,
      row_qb, row_kb, row_vb, nullptr, A1, A2, A3, 512, 512, 512);
  attn64<<<gAttn, 256, 0, stream>>>(A1, A2, A3, rrel, 1, 64);     // rowO -> A1

  // ---- col branch ----
  tranb3<<<dim3(16, 16, 3), tpb, 0, stream>>>(col_qw, col_kw, col_vw, wt_q, wt_k, wt_v);
  tranbP<<<dim3(16, 16), tpb, 0, stream>>>(col_pw, wt_p, 512);
  gemm256<0, true><<<gQKV, 512, 0, stream>>>(D0, D0, 999, wt_q, 512,
      col_qb, col_kb, col_vb, nullptr, A2, A3, D1, 512, 512, 512);
  attn64<<<gAttn, 256, 0, stream>>>(A2, A3, D1, crel, 64, 1);     // colO -> A2

  // ---- fused projection: out = x + rowO@rowPw + colO@colPw (K=1024) ----
  gemm256<2, false><<<gProj, 512, 0, stream>>>(A1, A2, 16, wt_p, 1024,
      row_pb, col_pb, nullptr, x, outp, nullptr, nullptr, 512, 1024, 512);

  // ---- FFN: K-split passes, hid = [32768][1024] in A1..A2 ----
  ln_k<0><<<8192, 256, 0, stream>>>(outp, l2g, l2b, nullptr, nullptr, A0, nullptr);
  tranb<<<dim3(64, 16), tpb, 0, stream>>>(ffw1, f1t, 512, 2048);   // [2048][512]
  tranb<<<dim3(16, 64), tpb, 0, stream>>>(ffw2, f2t, 2048, 512);   // [512][2048]
  // pass a: hid = gelu(ln2 @ W1[:, :1024]); out += hid @ W2[:1024, :] (+ffb2)
  gemm256<1, false><<<gFF1, 512, 0, stream>>>(A0, A0, 999, f1t, 512,
      ffb1, nullptr, nullptr, nullptr, hid, nullptr, nullptr, 1024, 512, 512);
  gemm256<2, false><<<gFF2, 512, 0, stream>>>(hid, hid, 999, f2t, 2048,
      ffb2, nullptr, nullptr, outp, outp, nullptr, nullptr, 512, 1024, 1024);
  // pass b: hid = gelu(ln2 @ W1[:, 1024:]); out += hid @ W2[1024:, :] (no bias)
  gemm256<1, false><<<gFF1, 512, 0, stream>>>(A0, A0, 999, f1t + (size_t)1024 * 512, 512,
      ffb1 + 1024, nullptr, nullptr, nullptr, hid, nullptr, nullptr, 1024, 512, 512);
  gemm256<2, false><<<gFF2, 512, 0, stream>>>(hid, hid, 999, f2t + 1024, 2048,
      nullptr, nullptr, nullptr, outp, outp, nullptr, nullptr, 512, 1024, 1024);
}

// Round 14
// 514.081 us; speedup vs baseline: 1.2444x; 1.2444x over previous
//
#include <hip/hip_runtime.h>

typedef unsigned short u16;
typedef unsigned int   u32;
typedef float  f32x4  __attribute__((ext_vector_type(4)));
typedef u32    u32x4  __attribute__((ext_vector_type(4)));
typedef __bf16 bf16x8 __attribute__((ext_vector_type(8)));

#define DEV __device__ __forceinline__

DEV float b2f(u16 u){ return __uint_as_float(((u32)u) << 16); }
DEV u16 f2b(float f){
  u32 u = __float_as_uint(f);
  u32 r = 0x7FFFu + ((u >> 16) & 1u);
  return (u16)((u + r) >> 16);
}
DEV u32 pack2(float a, float b){ return (u32)f2b(a) | ((u32)f2b(b) << 16); }
DEV uint4 pack8(const float* o){
  uint4 r;
  r.x = pack2(o[0], o[1]); r.y = pack2(o[2], o[3]);
  r.z = pack2(o[4], o[5]); r.w = pack2(o[6], o[7]);
  return r;
}

// D = A(16x32)*B(32x16)+C. A/B frag: lane holds 8 contiguous k
// (k = 8*(lane>>4)+e) of row/col (lane&15). C/D: col=lane&15,
// row=4*(lane>>4)+reg  [m89/m91-verified].
DEV f32x4 mfma16(u32x4 a, u32x4 b, f32x4 c){
  return __builtin_amdgcn_mfma_f32_16x16x32_bf16(
      __builtin_bit_cast(bf16x8, a), __builtin_bit_cast(bf16x8, b), c, 0, 0, 0);
}

DEV void gload16(const u16* g, u16* l){
  __builtin_amdgcn_global_load_lds((const __attribute__((address_space(1))) void*)(g),
                                   (__attribute__((address_space(3))) void*)(l), 16, 0, 0);
}

// ---------------------------------------------------------------- transposes
// 3 x [512][512] f32 -> bf16 transposed (QKV weights), batched via blockIdx.z
__global__ __launch_bounds__(256) void tranb3(
    const float* __restrict__ sA, const float* __restrict__ sB,
    const float* __restrict__ sC,
    u16* __restrict__ dA, u16* __restrict__ dB, u16* __restrict__ dC){
  __shared__ float tile[32][33];
  const float* src = (blockIdx.z == 0) ? sA : (blockIdx.z == 1) ? sB : sC;
  u16* dst = (blockIdx.z == 0) ? dA : (blockIdx.z == 1) ? dB : dC;
  const int bx = blockIdx.x * 32, by = blockIdx.y * 32;
  const int tx = threadIdx.x, ty = threadIdx.y;
#pragma unroll
  for (int i = 0; i < 4; ++i)
    tile[ty + i * 8][tx] = src[(size_t)(by + ty + i * 8) * 512 + bx + tx];
  __syncthreads();
#pragma unroll
  for (int i = 0; i < 4; ++i)
    dst[(size_t)(bx + ty + i * 8) * 512 + by + tx] = f2b(tile[tx][ty + i * 8]);
}

// [512][512] f32 -> dst[c*1024 + off + r] (fused projT, ld=1024, col offset)
__global__ __launch_bounds__(256) void tranbP(const float* __restrict__ src,
                                              u16* __restrict__ dst, int off){
  __shared__ float tile[32][33];
  const int bx = blockIdx.x * 32, by = blockIdx.y * 32;
  const int tx = threadIdx.x, ty = threadIdx.y;
#pragma unroll
  for (int i = 0; i < 4; ++i)
    tile[ty + i * 8][tx] = src[(size_t)(by + ty + i * 8) * 512 + bx + tx];
  __syncthreads();
#pragma unroll
  for (int i = 0; i < 4; ++i)
    dst[(size_t)(bx + ty + i * 8) * 1024 + off + by + tx] = f2b(tile[tx][ty + i * 8]);
}

// src [R][C] f32 -> dst [C][R] bf16 (FFN weights)
__global__ __launch_bounds__(256) void tranb(const float* __restrict__ src, u16* __restrict__ dst,
                                             int R, int C){
  __shared__ float tile[32][33];
  const int bx = blockIdx.x * 32, by = blockIdx.y * 32;
  const int tx = threadIdx.x, ty = threadIdx.y;
#pragma unroll
  for (int i = 0; i < 4; ++i)
    tile[ty + i * 8][tx] = src[(size_t)(by + ty + i * 8) * C + bx + tx];
  __syncthreads();
#pragma unroll
  for (int i = 0; i < 4; ++i)
    dst[(size_t)(bx + ty + i * 8) * R + by + tx] = f2b(tile[tx][ty + i * 8]);
}

// ---------------------------------------------------------------- layernorm
template<int TWO>
__global__ __launch_bounds__(256) void ln_k(const float* __restrict__ x,
    const float* __restrict__ g1, const float* __restrict__ b1,
    const float* __restrict__ g2, const float* __restrict__ b2,
    u16* __restrict__ y1, u16* __restrict__ y2){
  const int tid = threadIdx.x, lane = tid & 63, wv = tid >> 6;
  const size_t row  = (size_t)blockIdx.x * 4 + wv;
  const size_t boff = row * 512 + lane * 8;
  float f[8];
  {
    const f32x4* p = (const f32x4*)(x + boff);
    const f32x4 a = p[0], b = p[1];
#pragma unroll
    for (int j = 0; j < 4; ++j){ f[j] = a[j]; f[4 + j] = b[j]; }
  }
  float s1 = 0.f, s2 = 0.f;
#pragma unroll
  for (int j = 0; j < 8; ++j){ s1 += f[j]; s2 += f[j] * f[j]; }
#pragma unroll
  for (int off = 32; off > 0; off >>= 1){
    s1 += __shfl_xor(s1, off);
    s2 += __shfl_xor(s2, off);
  }
  const float m   = s1 * (1.0f / 512.0f);
  const float var = s2 * (1.0f / 512.0f) - m * m;
  const float inv = rsqrtf(var + 1e-4f);
  const int cb = lane * 8;
  float o[8];
#pragma unroll
  for (int j = 0; j < 8; ++j) o[j] = (f[j] - m) * inv * g1[cb + j] + b1[cb + j];
  *(uint4*)(y1 + boff) = pack8(o);
  if (TWO){
#pragma unroll
    for (int j = 0; j < 8; ++j) o[j] = (f[j] - m) * inv * g2[cb + j] + b2[cb + j];
    *(uint4*)(y2 + boff) = pack8(o);
  }
}

// ---------------------------------------------------------------- GEMM
// out = [A | A2nd](switch at K-tile nkA) @ Bt[N][K]^T + bias   (ldb == K)
// EPI 0: bf16 | 1: bf16+gelu | 2: f32 + opt 2nd bias (b1p) + f32 res.
// FUSE3: segmented bias per 512 cols AND split 512-stride output buffers.
// 128x128 tile, BK=64, 256 thr = 4 waves (2x2), wave tile 64x64
// (acc[4][4], 32.8 FLOP/LDS-byte -> MFMA-bound; was 64x32 @ 21.8 = LDS-bound).
// 64KB LDS double-buffered -> 2 blocks/CU (cross-block drain hiding, r9).
// T4 counted vmcnt(8), T2 XOR-8 swizzle (pre-swizzled global source,
// swizzled read), T5 setprio, T1 bijective XCD swizzle.
template<int EPI, bool FUSE3>
__global__ __launch_bounds__(256, 2) void gemm128(const u16* __restrict__ A,
    const u16* __restrict__ A2nd, int nkA,
    const u16* __restrict__ Bt,
    const float* __restrict__ b0p, const float* __restrict__ b1p,
    const float* __restrict__ b2p,
    const float* __restrict__ res,
    void* __restrict__ out0, void* __restrict__ out1, void* __restrict__ out2,
    int Nd, int K, int lda){
  __shared__ __align__(16) u16 smem[32768];       // 64 KB, reused by epilogue
  const int tid  = threadIdx.x;
  const int lane = tid & 63;
  const int lr = lane & 15, lg = lane >> 4;
  const int wave = tid >> 6;                      // 0..3
  const int wm = (wave >> 1) * 64, wn = (wave & 1) * 64;
  // T1: bijective XCD swizzle (all grids have nwg % 8 == 0)
  const u32 fd  = blockIdx.y * gridDim.x + blockIdx.x;
  const u32 cpx = (gridDim.x * gridDim.y) >> 3;
  const u32 T   = (fd & 7) * cpx + (fd >> 3);
  const int m0 = (T / gridDim.x) * 128, n0 = (T % gridDim.x) * 128;
  const int nk = K >> 6;

  f32x4 acc[4][4] = {};

  // LDS chunk (r, s) holds global chunk (r, s^(r&7)); reader inverts.
  auto stage = [&](int buf, int kt){
    const u16* Ap; int kb;
    if (kt < nkA){ Ap = A;    kb = kt * 64; }
    else         { Ap = A2nd; kb = (kt - nkA) * 64; }
    const int kbB = kt * 64;
    const int ao = buf * 8192, bo = 16384 + buf * 8192;
#pragma unroll
    for (int i = 0; i < 4; ++i){
      const int c = i * 256 + tid;
      const int r = c >> 3, gc = (c & 7) ^ (r & 7);
      gload16(Ap + (size_t)(m0 + r) * lda + kb + gc * 8, smem + ao + c * 8);
    }
#pragma unroll
    for (int i = 0; i < 4; ++i){
      const int c = i * 256 + tid;
      const int r = c >> 3, gc = (c & 7) ^ (r & 7);
      gload16(Bt + (size_t)(n0 + r) * K + kbB + gc * 8, smem + bo + c * 8);
    }
  };

  stage(0, 0);
  int cur = 0;
  for (int kt = 0; kt < nk; ++kt){
    if (kt + 1 < nk){
      stage(cur ^ 1, kt + 1);                          // issue next FIRST
      asm volatile("s_waitcnt vmcnt(8)" ::: "memory"); // tile kt resident
    } else {
      asm volatile("s_waitcnt vmcnt(0)" ::: "memory");
    }
    __builtin_amdgcn_s_barrier();
    __builtin_amdgcn_sched_barrier(0);
    const int ao = cur * 8192, bo = 16384 + cur * 8192;
#pragma unroll
    for (int kk = 0; kk < 2; ++kk){
      const int js = (kk * 4 + lg) ^ (lr & 7);         // unswizzle chunk
      u32x4 af[4], bf[4];
#pragma unroll
      for (int t = 0; t < 4; ++t)
        af[t] = *(const u32x4*)&smem[ao + (wm + t * 16 + lr) * 64 + js * 8];
#pragma unroll
      for (int t = 0; t < 4; ++t)
        bf[t] = *(const u32x4*)&smem[bo + (wn + t * 16 + lr) * 64 + js * 8];
      __builtin_amdgcn_s_setprio(1);
#pragma unroll
      for (int mt = 0; mt < 4; ++mt)
#pragma unroll
        for (int nt = 0; nt < 4; ++nt)
          acc[mt][nt] = mfma16(af[mt], bf[nt], acc[mt][nt]);
      __builtin_amdgcn_s_setprio(0);
    }
    asm volatile("" ::: "memory");                     // no LDS-read sinking
    __builtin_amdgcn_sched_barrier(0);
    __builtin_amdgcn_s_barrier();
    cur ^= 1;
  }

  if (EPI == 2){
    // f32 path: stage 128x128 f32 tile (64 KB), add residual in write phase
    float* Cf = (float*)smem;
#pragma unroll
    for (int mt = 0; mt < 4; ++mt)
#pragma unroll
      for (int nt = 0; nt < 4; ++nt){
        const int col = wn + nt * 16 + lr;
        float bv = b0p ? b0p[n0 + col] : 0.0f;
        if (b1p) bv += b1p[n0 + col];
#pragma unroll
        for (int r = 0; r < 4; ++r)
          Cf[(wm + mt * 16 + lg * 4 + r) * 128 + col] = acc[mt][nt][r] + bv;
      }
    __syncthreads();
    float* o = (float*)out0;
#pragma unroll
    for (int p = 0; p < 16; ++p){
      const int rr = p * 8 + (tid >> 5);
      const int cc = (tid & 31) * 4;
      f32x4 c = *(f32x4*)&Cf[rr * 128 + cc];
      const size_t gi = (size_t)(m0 + rr) * Nd + n0 + cc;
      c += *(const f32x4*)(res + gi);
      *(f32x4*)(o + gi) = c;
    }
  } else {
    // bf16 path: stage 128x(128+8) u16 tile
    u16* Cl = smem;
#pragma unroll
    for (int mt = 0; mt < 4; ++mt)
#pragma unroll
      for (int nt = 0; nt < 4; ++nt){
        const int col = n0 + wn + nt * 16 + lr;
        float bv;
        if (FUSE3){
          if (col >= 1024)      bv = b2p[col - 1024];
          else if (col >= 512)  bv = b1p[col - 512];
          else                  bv = b0p[col];
        } else bv = b0p[col];
#pragma unroll
        for (int r = 0; r < 4; ++r){
          float v2 = acc[mt][nt][r] + bv;
          if (EPI == 1) v2 = 0.5f * v2 * (1.0f + erff(v2 * 0.70710678118654752f));
          Cl[(wm + mt * 16 + lg * 4 + r) * 136 + wn + nt * 16 + lr] = f2b(v2);
        }
      }
    __syncthreads();
    u16* o = (u16*)out0;
    int ncol = n0;
    if (FUSE3){
      const int grp = n0 >> 9;
      o = (u16*)(grp == 0 ? out0 : grp == 1 ? out1 : out2);
      ncol = n0 & 511;
    }
#pragma unroll
    for (int p = 0; p < 8; ++p){
      const int rr = p * 16 + (tid >> 4);
      const int cc = (tid & 15) * 8;
      *(uint4*)(o + (size_t)(m0 + rr) * (FUSE3 ? 512 : Nd) + ncol + cc) =
          *(uint4*)&Cl[rr * 136 + cc];
    }
  }
}

// ---------------------------------------------------------------- attention
// One block per (sequence, head). T=64, hd=64, 4 waves. Writes output
// IN-PLACE over q. Token t -> row base + t*tstr.
__global__ __launch_bounds__(256, 2) void attn64(u16* __restrict__ q,
    const u16* __restrict__ k, const u16* __restrict__ v,
    const float* __restrict__ relw,
    int sscale, int tstr){
  __shared__ __align__(16) u16 Qs[64 * 80];
  __shared__ __align__(16) u16 Ks[64 * 80];
  __shared__ __align__(16) u16 Vt[64 * 80];   // V transposed: Vt[d][t]
  __shared__ __align__(16) u16 Ps[64 * 80];
  __shared__ float Ss[64 * 68];
  __shared__ float tb[128];

  const int s = blockIdx.x, head = blockIdx.y;
  const int tid = threadIdx.x;
  const int lane = tid & 63, wv = tid >> 6;
  const int lr = lane & 15, lg = lane >> 4;
  const int base = (s >> 6) * 4096 + (s & 63) * sscale;

  if (tid < 127) tb[tid] = relw[tid * 8 + head];

#pragma unroll
  for (int rep = 0; rep < 2; ++rep){
    const int e = rep * 2048 + tid * 8;
    const int t = e >> 6, c = e & 63;
    const size_t goff = (size_t)(base + t * tstr) * 512 + head * 64 + c;
    *(uint4*)&Qs[t * 80 + c] = *(const uint4*)(q + goff);
    *(uint4*)&Ks[t * 80 + c] = *(const uint4*)(k + goff);
    const uint4 vvv = *(const uint4*)(v + goff);
    u32 w;
    w = vvv.x; Vt[(c + 0) * 80 + t] = (u16)w; Vt[(c + 1) * 80 + t] = (u16)(w >> 16);
    w = vvv.y; Vt[(c + 2) * 80 + t] = (u16)w; Vt[(c + 3) * 80 + t] = (u16)(w >> 16);
    w = vvv.z; Vt[(c + 4) * 80 + t] = (u16)w; Vt[(c + 5) * 80 + t] = (u16)(w >> 16);
    w = vvv.w; Vt[(c + 6) * 80 + t] = (u16)w; Vt[(c + 7) * 80 + t] = (u16)(w >> 16);
  }
  __syncthreads();

  const int i0 = wv * 16;
  u32x4 af[2];
#pragma unroll
  for (int kk = 0; kk < 2; ++kk)
    af[kk] = *(const u32x4*)&Qs[(i0 + lr) * 80 + kk * 32 + lg * 8];
#pragma unroll
  for (int jt = 0; jt < 4; ++jt){
    f32x4 acc = {};
#pragma unroll
    for (int kk = 0; kk < 2; ++kk){
      const u32x4 bf = *(const u32x4*)&Ks[(jt * 16 + lr) * 80 + kk * 32 + lg * 8];
      acc = mfma16(af[kk], bf, acc);
    }
#pragma unroll
    for (int r = 0; r < 4; ++r){
      const int i = i0 + lg * 4 + r;
      const int j = jt * 16 + lr;
      Ss[i * 68 + j] = acc[r] * 0.125f + tb[j - i + 63];
    }
  }
  __syncthreads();

  {
    const int rr = tid >> 2, cp = tid & 3;
    float ev[16];
    float mx = -3.0e38f;
#pragma unroll
    for (int u = 0; u < 16; ++u){ ev[u] = Ss[rr * 68 + cp * 16 + u]; mx = fmaxf(mx, ev[u]); }
    mx = fmaxf(mx, __shfl_xor(mx, 1, 4));
    mx = fmaxf(mx, __shfl_xor(mx, 2, 4));
    float sum = 0.f;
#pragma unroll
    for (int u = 0; u < 16; ++u){ ev[u] = expf(ev[u] - mx); sum += ev[u]; }
    sum += __shfl_xor(sum, 1, 4);
    sum += __shfl_xor(sum, 2, 4);
    const float inv = 1.0f / sum;
#pragma unroll
    for (int u = 0; u < 16; ++u) Ps[rr * 80 + cp * 16 + u] = f2b(ev[u] * inv);
  }
  __syncthreads();

  u32x4 pa[2];
#pragma unroll
  for (int kk = 0; kk < 2; ++kk)
    pa[kk] = *(const u32x4*)&Ps[(i0 + lr) * 80 + kk * 32 + lg * 8];
#pragma unroll
  for (int dt = 0; dt < 4; ++dt){
    f32x4 acc = {};
#pragma unroll
    for (int kk = 0; kk < 2; ++kk){
      const u32x4 bf = *(const u32x4*)&Vt[(dt * 16 + lr) * 80 + kk * 32 + lg * 8];
      acc = mfma16(pa[kk], bf, acc);
    }
#pragma unroll
    for (int r = 0; r < 4; ++r)
      Qs[(i0 + lg * 4 + r) * 80 + dt * 16 + lr] = f2b(acc[r]);
  }
  __syncthreads();

#pragma unroll
  for (int p = 0; p < 2; ++p){
    const int rr = p * 32 + (tid >> 3);
    const int cc = (tid & 7) * 8;
    *(uint4*)(q + (size_t)(base + rr * tstr) * 512 + head * 64 + cc) =
        *(uint4*)&Qs[rr * 80 + cc];
  }
}

// ---------------------------------------------------------------- launcher
extern "C" void kernel_launch(void* const* d_in, const int* in_sizes, int n_in,
                              void* d_out, int out_size, void* d_ws, size_t ws_size,
                              hipStream_t stream){
  const float* x      = (const float*)d_in[0];
  const float* row_qw = (const float*)d_in[1];  const float* row_qb = (const float*)d_in[2];
  const float* row_kw = (const float*)d_in[3];  const float* row_kb = (const float*)d_in[4];
  const float* row_vw = (const float*)d_in[5];  const float* row_vb = (const float*)d_in[6];
  const float* row_pw = (const float*)d_in[7];  const float* row_pb = (const float*)d_in[8];
  const float* col_qw = (const float*)d_in[9];  const float* col_qb = (const float*)d_in[10];
  const float* col_kw = (const float*)d_in[11]; const float* col_kb = (const float*)d_in[12];
  const float* col_vw = (const float*)d_in[13]; const float* col_vb = (const float*)d_in[14];
  const float* col_pw = (const float*)d_in[15]; const float* col_pb = (const float*)d_in[16];
  const float* rg  = (const float*)d_in[17]; const float* rb  = (const float*)d_in[18];
  const float* cg  = (const float*)d_in[19]; const float* cb  = (const float*)d_in[20];
  const float* l2g = (const float*)d_in[21]; const float* l2b = (const float*)d_in[22];
  const float* ffw1 = (const float*)d_in[23]; const float* ffb1 = (const float*)d_in[24];
  const float* ffw2 = (const float*)d_in[25]; const float* ffb2 = (const float*)d_in[26];
  const float* rrel = (const float*)d_in[27]; const float* crel = (const float*)d_in[28];
  float* outp = (float*)d_out;
  u16* outp16 = (u16*)d_out;

  const size_t ACT = (size_t)32768 * 512;          // activation buffer (elems)
  const size_t W55 = (size_t)512 * 512;
  const size_t NEED = (4 * ACT + 8 * W55) * 2;     // bytes = 138,412,032
  if (ws_size < NEED) return;                      // sentinel: d_out stays 0

  u16* A0 = (u16*)d_ws;        // rowLN / ln2 out
  u16* A1 = A0 + ACT;          // rowQ -> rowO ; FFN hid
  u16* A2 = A1 + ACT;          // rowK ; colQ -> colO
  u16* A3 = A2 + ACT;          // rowV ; colK
  u16* D0 = outp16;            // colLN (bf16 scratch in d_out, dies at proj)
  u16* D1 = outp16 + ACT;      // colV  (bf16 scratch in d_out, dies at proj)
  u16* wtb = A3 + ACT;         // weight area: 8 x W55
  u16* wt_q = wtb;  u16* wt_k = wtb + W55;  u16* wt_v = wtb + 2 * W55;
  u16* wt_p = wtb + 3 * W55;   // fused projT [512][1024] = 2 slots (3..4)
  u16* f1t  = wtb;             // FF phase: [2048][512] = 4 slots (0..3)
  u16* f2t  = wtb + 4 * W55;   // FF phase: [512][2048] = 4 slots (4..7)

  const dim3 tpb(32, 8);
  const dim3 gQKV(12, 256);    // N=1536 fused, 3072 blocks (%8==0)
  const dim3 gProj(4, 256);    // 1024 blocks
  const dim3 gAttn(512, 8);

  // ---- prologue: both LNs in one pass (x read once) ----
  ln_k<1><<<8192, 256, 0, stream>>>(x, rg, rb, cg, cb, A0, D0);

  // ---- row branch ----
  tranb3<<<dim3(16, 16, 3), tpb, 0, stream>>>(row_qw, row_kw, row_vw, wt_q, wt_k, wt_v);
  tranbP<<<dim3(16, 16), tpb, 0, stream>>>(row_pw, wt_p, 0);
  gemm128<0, true><<<gQKV, 256, 0, stream>>>(A0, A0, 99, wt_q, row_qb, row_kb, row_vb,
                                             nullptr, A1, A2, A3, 512, 512, 512);
  attn64<<<gAttn, 256, 0, stream>>>(A1, A2, A3, rrel, 1, 64);     // rowO -> A1

  // ---- col branch ----
  tranb3<<<dim3(16, 16, 3), tpb, 0, stream>>>(col_qw, col_kw, col_vw, wt_q, wt_k, wt_v);
  tranbP<<<dim3(16, 16), tpb, 0, stream>>>(col_pw, wt_p, 512);
  gemm128<0, true><<<gQKV, 256, 0, stream>>>(D0, D0, 99, wt_q, col_qb, col_kb, col_vb,
                                             nullptr, A2, A3, D1, 512, 512, 512);
  attn64<<<gAttn, 256, 0, stream>>>(A2, A3, D1, crel, 64, 1);     // colO -> A2

  // ---- fused projection: out = x + rowO@rowPw + colO@colPw (K=1024) ----
  gemm128<2, false><<<gProj, 256, 0, stream>>>(A1, A2, 8, wt_p, row_pb, col_pb,
                                               nullptr, x, outp, nullptr, nullptr,
                                               512, 1024, 512);

  // ---- FFN (2 chunks of 16384 rows; hid = A1..A2) ----
  ln_k<0><<<8192, 256, 0, stream>>>(outp, l2g, l2b, nullptr, nullptr, A0, nullptr);
  tranb<<<dim3(64, 16), tpb, 0, stream>>>(ffw1, f1t, 512, 2048);   // [2048][512]
  tranb<<<dim3(16, 64), tpb, 0, stream>>>(ffw2, f2t, 2048, 512);   // [512][2048]
  for (int c = 0; c < 2; ++c){
    const size_t ro = (size_t)c * 16384;
    gemm128<1, false><<<dim3(16, 128), 256, 0, stream>>>(A0 + ro * 512, A0, 99, f1t,
        ffb1, nullptr, nullptr, nullptr, A1, nullptr, nullptr, 2048, 512, 512);
    gemm128<2, false><<<dim3(4, 128), 256, 0, stream>>>(A1, A1, 99, f2t,
        ffb2, nullptr, nullptr, outp + ro * 512, outp + ro * 512, nullptr, nullptr,
        512, 2048, 2048);
  }
}

// Round 15
// 471.961 us; speedup vs baseline: 1.3554x; 1.0892x over previous
//
#include <hip/hip_runtime.h>

typedef unsigned short u16;
typedef unsigned int   u32;
typedef float  f32x4  __attribute__((ext_vector_type(4)));
typedef u32    u32x4  __attribute__((ext_vector_type(4)));
typedef __bf16 bf16x8 __attribute__((ext_vector_type(8)));

#define DEV __device__ __forceinline__

DEV float b2f(u16 u){ return __uint_as_float(((u32)u) << 16); }
DEV u16 f2b(float f){
  u32 u = __float_as_uint(f);
  u32 r = 0x7FFFu + ((u >> 16) & 1u);
  return (u16)((u + r) >> 16);
}
DEV u32 pack2(float a, float b){ return (u32)f2b(a) | ((u32)f2b(b) << 16); }
DEV uint4 pack8(const float* o){
  uint4 r;
  r.x = pack2(o[0], o[1]); r.y = pack2(o[2], o[3]);
  r.z = pack2(o[4], o[5]); r.w = pack2(o[6], o[7]);
  return r;
}

// D = A(16x32)*B(32x16)+C. A/B frag: lane holds 8 contiguous k
// (k = 8*(lane>>4)+e) of row/col (lane&15). C/D: col=lane&15,
// row=4*(lane>>4)+reg  [m89/m91-verified].
DEV f32x4 mfma16(u32x4 a, u32x4 b, f32x4 c){
  return __builtin_amdgcn_mfma_f32_16x16x32_bf16(
      __builtin_bit_cast(bf16x8, a), __builtin_bit_cast(bf16x8, b), c, 0, 0, 0);
}

DEV void gload16(const u16* g, u16* l){
  __builtin_amdgcn_global_load_lds((const __attribute__((address_space(1))) void*)(g),
                                   (__attribute__((address_space(3))) void*)(l), 16, 0, 0);
}

// ---------------------------------------------------------------- transposes
// 3 x [512][512] f32 -> bf16 transposed (QKV weights), batched via blockIdx.z
__global__ __launch_bounds__(256) void tranb3(
    const float* __restrict__ sA, const float* __restrict__ sB,
    const float* __restrict__ sC,
    u16* __restrict__ dA, u16* __restrict__ dB, u16* __restrict__ dC){
  __shared__ float tile[32][33];
  const float* src = (blockIdx.z == 0) ? sA : (blockIdx.z == 1) ? sB : sC;
  u16* dst = (blockIdx.z == 0) ? dA : (blockIdx.z == 1) ? dB : dC;
  const int bx = blockIdx.x * 32, by = blockIdx.y * 32;
  const int tx = threadIdx.x, ty = threadIdx.y;
#pragma unroll
  for (int i = 0; i < 4; ++i)
    tile[ty + i * 8][tx] = src[(size_t)(by + ty + i * 8) * 512 + bx + tx];
  __syncthreads();
#pragma unroll
  for (int i = 0; i < 4; ++i)
    dst[(size_t)(bx + ty + i * 8) * 512 + by + tx] = f2b(tile[tx][ty + i * 8]);
}

// [512][512] f32 -> dst[c*1024 + off + r] (fused projT, ld=1024, col offset)
__global__ __launch_bounds__(256) void tranbP(const float* __restrict__ src,
                                              u16* __restrict__ dst, int off){
  __shared__ float tile[32][33];
  const int bx = blockIdx.x * 32, by = blockIdx.y * 32;
  const int tx = threadIdx.x, ty = threadIdx.y;
#pragma unroll
  for (int i = 0; i < 4; ++i)
    tile[ty + i * 8][tx] = src[(size_t)(by + ty + i * 8) * 512 + bx + tx];
  __syncthreads();
#pragma unroll
  for (int i = 0; i < 4; ++i)
    dst[(size_t)(bx + ty + i * 8) * 1024 + off + by + tx] = f2b(tile[tx][ty + i * 8]);
}

// src [R][C] f32 -> dst [C][R] bf16 (FFN weights)
__global__ __launch_bounds__(256) void tranb(const float* __restrict__ src, u16* __restrict__ dst,
                                             int R, int C){
  __shared__ float tile[32][33];
  const int bx = blockIdx.x * 32, by = blockIdx.y * 32;
  const int tx = threadIdx.x, ty = threadIdx.y;
#pragma unroll
  for (int i = 0; i < 4; ++i)
    tile[ty + i * 8][tx] = src[(size_t)(by + ty + i * 8) * C + bx + tx];
  __syncthreads();
#pragma unroll
  for (int i = 0; i < 4; ++i)
    dst[(size_t)(bx + ty + i * 8) * R + by + tx] = f2b(tile[tx][ty + i * 8]);
}

// ---------------------------------------------------------------- layernorm
// One wave per 512-elem row. f32 in -> bf16 out. TWO=1: two gamma/beta sets.
template<int TWO>
__global__ __launch_bounds__(256) void ln_k(const float* __restrict__ x,
    const float* __restrict__ g1, const float* __restrict__ b1,
    const float* __restrict__ g2, const float* __restrict__ b2,
    u16* __restrict__ y1, u16* __restrict__ y2){
  const int tid = threadIdx.x, lane = tid & 63, wv = tid >> 6;
  const size_t row  = (size_t)blockIdx.x * 4 + wv;
  const size_t boff = row * 512 + lane * 8;
  float f[8];
  {
    const f32x4* p = (const f32x4*)(x + boff);
    const f32x4 a = p[0], b = p[1];
#pragma unroll
    for (int j = 0; j < 4; ++j){ f[j] = a[j]; f[4 + j] = b[j]; }
  }
  float s1 = 0.f, s2 = 0.f;
#pragma unroll
  for (int j = 0; j < 8; ++j){ s1 += f[j]; s2 += f[j] * f[j]; }
#pragma unroll
  for (int off = 32; off > 0; off >>= 1){
    s1 += __shfl_xor(s1, off);
    s2 += __shfl_xor(s2, off);
  }
  const float m   = s1 * (1.0f / 512.0f);
  const float var = s2 * (1.0f / 512.0f) - m * m;
  const float inv = rsqrtf(var + 1e-4f);
  const int cb = lane * 8;
  float o[8];
#pragma unroll
  for (int j = 0; j < 8; ++j) o[j] = (f[j] - m) * inv * g1[cb + j] + b1[cb + j];
  *(uint4*)(y1 + boff) = pack8(o);
  if (TWO){
#pragma unroll
    for (int j = 0; j < 8; ++j) o[j] = (f[j] - m) * inv * g2[cb + j] + b2[cb + j];
    *(uint4*)(y2 + boff) = pack8(o);
  }
}

// ---------------------------------------------------------------- GEMM
// out = [A | A2nd](M x K, switch at K-tile nkA) @ Bt[N][K]^T + bias
// EPI 0: bf16 | 1: bf16+gelu | 2: f32 + opt 2nd bias + f32 res.
// FUSE3: segmented bias per 512 cols AND split output buffers per 512 cols.
// 128x128 tile, BK=64, 512 thr = 8 waves (2Mx4N, 64x32 each), 64KB LDS
// double-buffered -> 2 blocks/CU. T4 counted vmcnt(4), T2 XOR-8 swizzle
// (pre-swizzled global source, swizzled read), T5 setprio, T1 XCD swizzle.
// [Session optimum: r9/r10 measured 474 us; all geometry departures
//  (256^2 1-block/CU, BK=32, 4-wave 64x64, 3-slot deep pipeline) regressed.]
template<int EPI, bool FUSE3>
__global__ __launch_bounds__(512, 2) void gemm128(const u16* __restrict__ A,
    const u16* __restrict__ A2nd, int nkA,
    const u16* __restrict__ Bt,
    const float* __restrict__ b0p, const float* __restrict__ b1p,
    const float* __restrict__ b2p,
    const float* __restrict__ res,
    void* __restrict__ out0, void* __restrict__ out1, void* __restrict__ out2,
    int Nd, int K, int lda){
  __shared__ __align__(16) u16 smem[32768];       // 64 KB, reused by epilogue
  const int tid  = threadIdx.x;
  const int lane = tid & 63;
  const int lr = lane & 15, lg = lane >> 4;
  const int wave = tid >> 6;
  const int wm = (wave >> 2) * 64, wn = (wave & 3) * 32;
  // T1: bijective XCD swizzle (all grids have nwg % 8 == 0)
  const u32 fd  = blockIdx.y * gridDim.x + blockIdx.x;
  const u32 cpx = (gridDim.x * gridDim.y) >> 3;
  const u32 T   = (fd & 7) * cpx + (fd >> 3);
  const int m0 = (T / gridDim.x) * 128, n0 = (T % gridDim.x) * 128;
  const int nk = K >> 6;

  f32x4 acc[4][2] = {};

  // LDS chunk (r, s) holds global chunk (r, s^(r&7)); reader inverts.
  auto stage = [&](int buf, int kt){
    const u16* Ap; int kb;
    if (kt < nkA){ Ap = A;    kb = kt * 64; }
    else         { Ap = A2nd; kb = (kt - nkA) * 64; }
    const int kbB = kt * 64;
    const int ao = buf * 8192, bo = 16384 + buf * 8192;
#pragma unroll
    for (int i = 0; i < 2; ++i){
      const int c = i * 512 + tid;
      const int r = c >> 3, gc = (c & 7) ^ (r & 7);
      gload16(Ap + (size_t)(m0 + r) * lda + kb + gc * 8, smem + ao + c * 8);
    }
#pragma unroll
    for (int i = 0; i < 2; ++i){
      const int c = i * 512 + tid;
      const int r = c >> 3, gc = (c & 7) ^ (r & 7);
      gload16(Bt + (size_t)(n0 + r) * K + kbB + gc * 8, smem + bo + c * 8);
    }
  };

  stage(0, 0);
  int cur = 0;
  for (int kt = 0; kt < nk; ++kt){
    if (kt + 1 < nk){
      stage(cur ^ 1, kt + 1);                          // issue next FIRST
      asm volatile("s_waitcnt vmcnt(4)" ::: "memory"); // tile kt done, kt+1 in flight
    } else {
      asm volatile("s_waitcnt vmcnt(0)" ::: "memory");
    }
    __builtin_amdgcn_s_barrier();
    __builtin_amdgcn_sched_barrier(0);
    const int ao = cur * 8192, bo = 16384 + cur * 8192;
#pragma unroll
    for (int kk = 0; kk < 2; ++kk){
      u32x4 af[4], bf[2];
#pragma unroll
      for (int t = 0; t < 4; ++t){
        const int js = (kk * 4 + lg) ^ (lr & 7);       // unswizzle chunk
        af[t] = *(const u32x4*)&smem[ao + (wm + t * 16 + lr) * 64 + js * 8];
      }
#pragma unroll
      for (int t = 0; t < 2; ++t){
        const int js = (kk * 4 + lg) ^ (lr & 7);
        bf[t] = *(const u32x4*)&smem[bo + (wn + t * 16 + lr) * 64 + js * 8];
      }
      __builtin_amdgcn_s_setprio(1);
#pragma unroll
      for (int mt = 0; mt < 4; ++mt)
#pragma unroll
        for (int nt = 0; nt < 2; ++nt)
          acc[mt][nt] = mfma16(af[mt], bf[nt], acc[mt][nt]);
      __builtin_amdgcn_s_setprio(0);
    }
    asm volatile("" ::: "memory");                     // no LDS-read sinking
    __builtin_amdgcn_sched_barrier(0);
    __builtin_amdgcn_s_barrier();
    cur ^= 1;
  }

  if (EPI == 2){
    // f32 path: stage 128x128 f32 tile (64 KB), add residual in write phase
    float* Cf = (float*)smem;
#pragma unroll
    for (int mt = 0; mt < 4; ++mt)
#pragma unroll
      for (int nt = 0; nt < 2; ++nt){
        const int col = wn + nt * 16 + lr;
        float bv = b0p[n0 + col];
        if (b1p) bv += b1p[n0 + col];
#pragma unroll
        for (int r = 0; r < 4; ++r)
          Cf[(wm + mt * 16 + lg * 4 + r) * 128 + col] = acc[mt][nt][r] + bv;
      }
    __syncthreads();
    float* o = (float*)out0;
#pragma unroll
    for (int p = 0; p < 8; ++p){
      const int rr = p * 16 + (tid >> 5);
      const int cc = (tid & 31) * 4;
      f32x4 c = *(f32x4*)&Cf[rr * 128 + cc];
      const size_t gi = (size_t)(m0 + rr) * Nd + n0 + cc;
      c += *(const f32x4*)(res + gi);
      *(f32x4*)(o + gi) = c;
    }
  } else {
    // bf16 path: stage 128x(128+8) u16 tile
    u16* Cl = smem;
#pragma unroll
    for (int mt = 0; mt < 4; ++mt)
#pragma unroll
      for (int nt = 0; nt < 2; ++nt){
        const int col = n0 + wn + nt * 16 + lr;
        float bv;
        if (FUSE3){
          if (col >= 1024)      bv = b2p[col - 1024];
          else if (col >= 512)  bv = b1p[col - 512];
          else                  bv = b0p[col];
        } else bv = b0p[col];
#pragma unroll
        for (int r = 0; r < 4; ++r){
          float v2 = acc[mt][nt][r] + bv;
          if (EPI == 1) v2 = 0.5f * v2 * (1.0f + erff(v2 * 0.70710678118654752f));
          Cl[(wm + mt * 16 + lg * 4 + r) * 136 + wn + nt * 16 + lr] = f2b(v2);
        }
      }
    __syncthreads();
    u16* o = (u16*)out0;
    int ncol = n0;
    if (FUSE3){
      const int grp = n0 >> 9;
      o = (u16*)(grp == 0 ? out0 : grp == 1 ? out1 : out2);
      ncol = n0 & 511;
    }
#pragma unroll
    for (int p = 0; p < 4; ++p){
      const int rr = p * 32 + (tid >> 4);
      const int cc = (tid & 15) * 8;
      *(uint4*)(o + (size_t)(m0 + rr) * (FUSE3 ? 512 : Nd) + ncol + cc) =
          *(uint4*)&Cl[rr * 136 + cc];
    }
  }
}

// ---------------------------------------------------------------- attention
// One block per (sequence, head). T=64, hd=64, 4 waves. Separate q/k/v
// buffers (row stride 512). Writes output IN-PLACE over q (block reads its
// own (s,head) slice into LDS first; slices disjoint across blocks).
// Token t -> row base + t*tstr, base = (s>>6)*4096 + (s&63)*sscale.
__global__ __launch_bounds__(256, 2) void attn64(u16* __restrict__ q,
    const u16* __restrict__ k, const u16* __restrict__ v,
    const float* __restrict__ relw,
    int sscale, int tstr){
  __shared__ __align__(16) u16 Qs[64 * 80];
  __shared__ __align__(16) u16 Ks[64 * 80];
  __shared__ __align__(16) u16 Vt[64 * 80];   // V transposed: Vt[d][t]
  __shared__ __align__(16) u16 Ps[64 * 80];
  __shared__ float Ss[64 * 68];
  __shared__ float tb[128];

  const int s = blockIdx.x, head = blockIdx.y;
  const int tid = threadIdx.x;
  const int lane = tid & 63, wv = tid >> 6;
  const int lr = lane & 15, lg = lane >> 4;
  const int base = (s >> 6) * 4096 + (s & 63) * sscale;

  if (tid < 127) tb[tid] = relw[tid * 8 + head];

#pragma unroll
  for (int rep = 0; rep < 2; ++rep){
    const int e = rep * 2048 + tid * 8;
    const int t = e >> 6, c = e & 63;
    const size_t goff = (size_t)(base + t * tstr) * 512 + head * 64 + c;
    *(uint4*)&Qs[t * 80 + c] = *(const uint4*)(q + goff);
    *(uint4*)&Ks[t * 80 + c] = *(const uint4*)(k + goff);
    const uint4 vvv = *(const uint4*)(v + goff);
    u32 w;
    w = vvv.x; Vt[(c + 0) * 80 + t] = (u16)w; Vt[(c + 1) * 80 + t] = (u16)(w >> 16);
    w = vvv.y; Vt[(c + 2) * 80 + t] = (u16)w; Vt[(c + 3) * 80 + t] = (u16)(w >> 16);
    w = vvv.z; Vt[(c + 4) * 80 + t] = (u16)w; Vt[(c + 5) * 80 + t] = (u16)(w >> 16);
    w = vvv.w; Vt[(c + 6) * 80 + t] = (u16)w; Vt[(c + 7) * 80 + t] = (u16)(w >> 16);
  }
  __syncthreads();

  const int i0 = wv * 16;
  // S = Q K^T * 0.125 + rel
  u32x4 af[2];
#pragma unroll
  for (int kk = 0; kk < 2; ++kk)
    af[kk] = *(const u32x4*)&Qs[(i0 + lr) * 80 + kk * 32 + lg * 8];
#pragma unroll
  for (int jt = 0; jt < 4; ++jt){
    f32x4 acc = {};
#pragma unroll
    for (int kk = 0; kk < 2; ++kk){
      const u32x4 bf = *(const u32x4*)&Ks[(jt * 16 + lr) * 80 + kk * 32 + lg * 8];
      acc = mfma16(af[kk], bf, acc);
    }
#pragma unroll
    for (int r = 0; r < 4; ++r){
      const int i = i0 + lg * 4 + r;
      const int j = jt * 16 + lr;
      Ss[i * 68 + j] = acc[r] * 0.125f + tb[j - i + 63];
    }
  }
  __syncthreads();

  // softmax: 4 lanes per row
  {
    const int rr = tid >> 2, cp = tid & 3;
    float ev[16];
    float mx = -3.0e38f;
#pragma unroll
    for (int u = 0; u < 16; ++u){ ev[u] = Ss[rr * 68 + cp * 16 + u]; mx = fmaxf(mx, ev[u]); }
    mx = fmaxf(mx, __shfl_xor(mx, 1, 4));
    mx = fmaxf(mx, __shfl_xor(mx, 2, 4));
    float sum = 0.f;
#pragma unroll
    for (int u = 0; u < 16; ++u){ ev[u] = expf(ev[u] - mx); sum += ev[u]; }
    sum += __shfl_xor(sum, 1, 4);
    sum += __shfl_xor(sum, 2, 4);
    const float inv = 1.0f / sum;
#pragma unroll
    for (int u = 0; u < 16; ++u) Ps[rr * 80 + cp * 16 + u] = f2b(ev[u] * inv);
  }
  __syncthreads();

  // O = P V -> stage into Qs
  u32x4 pa[2];
#pragma unroll
  for (int kk = 0; kk < 2; ++kk)
    pa[kk] = *(const u32x4*)&Ps[(i0 + lr) * 80 + kk * 32 + lg * 8];
#pragma unroll
  for (int dt = 0; dt < 4; ++dt){
    f32x4 acc = {};
#pragma unroll
    for (int kk = 0; kk < 2; ++kk){
      const u32x4 bf = *(const u32x4*)&Vt[(dt * 16 + lr) * 80 + kk * 32 + lg * 8];
      acc = mfma16(pa[kk], bf, acc);
    }
#pragma unroll
    for (int r = 0; r < 4; ++r)
      Qs[(i0 + lg * 4 + r) * 80 + dt * 16 + lr] = f2b(acc[r]);
  }
  __syncthreads();

  // coalesced out-write: 128 B per row (whole head slice), over q
#pragma unroll
  for (int p = 0; p < 2; ++p){
    const int rr = p * 32 + (tid >> 3);
    const int cc = (tid & 7) * 8;
    *(uint4*)(q + (size_t)(base + rr * tstr) * 512 + head * 64 + cc) =
        *(uint4*)&Qs[rr * 80 + cc];
  }
}

// ---------------------------------------------------------------- launcher
extern "C" void kernel_launch(void* const* d_in, const int* in_sizes, int n_in,
                              void* d_out, int out_size, void* d_ws, size_t ws_size,
                              hipStream_t stream){
  const float* x      = (const float*)d_in[0];
  const float* row_qw = (const float*)d_in[1];  const float* row_qb = (const float*)d_in[2];
  const float* row_kw = (const float*)d_in[3];  const float* row_kb = (const float*)d_in[4];
  const float* row_vw = (const float*)d_in[5];  const float* row_vb = (const float*)d_in[6];
  const float* row_pw = (const float*)d_in[7];  const float* row_pb = (const float*)d_in[8];
  const float* col_qw = (const float*)d_in[9];  const float* col_qb = (const float*)d_in[10];
  const float* col_kw = (const float*)d_in[11]; const float* col_kb = (const float*)d_in[12];
  const float* col_vw = (const float*)d_in[13]; const float* col_vb = (const float*)d_in[14];
  const float* col_pw = (const float*)d_in[15]; const float* col_pb = (const float*)d_in[16];
  const float* rg  = (const float*)d_in[17]; const float* rb  = (const float*)d_in[18];
  const float* cg  = (const float*)d_in[19]; const float* cb  = (const float*)d_in[20];
  const float* l2g = (const float*)d_in[21]; const float* l2b = (const float*)d_in[22];
  const float* ffw1 = (const float*)d_in[23]; const float* ffb1 = (const float*)d_in[24];
  const float* ffw2 = (const float*)d_in[25]; const float* ffb2 = (const float*)d_in[26];
  const float* rrel = (const float*)d_in[27]; const float* crel = (const float*)d_in[28];
  float* outp = (float*)d_out;
  u16* outp16 = (u16*)d_out;

  const size_t ACT = (size_t)32768 * 512;          // activation buffer (elems)
  const size_t W55 = (size_t)512 * 512;
  const size_t NEED = (4 * ACT + 8 * W55) * 2;     // bytes = 138,412,032
  if (ws_size < NEED) return;                      // sentinel: d_out stays 0

  u16* A0 = (u16*)d_ws;        // rowLN / ln2 out
  u16* A1 = A0 + ACT;          // rowQ -> rowO ; FFN hid chunk
  u16* A2 = A1 + ACT;          // rowK ; colQ -> colO
  u16* A3 = A2 + ACT;          // rowV ; colK
  u16* D0 = outp16;            // colLN (bf16 scratch in d_out, dies at proj)
  u16* D1 = outp16 + ACT;      // colV  (bf16 scratch in d_out, dies at proj)
  u16* wtb = A3 + ACT;         // weight area: 8 x W55
  u16* wt_q = wtb;  u16* wt_k = wtb + W55;  u16* wt_v = wtb + 2 * W55;
  u16* wt_p = wtb + 3 * W55;   // fused projT [512][1024] = 2 slots (3..4)
  u16* f1t  = wtb;             // FF phase: [2048][512] = 4 slots (0..3)
  u16* f2t  = wtb + 4 * W55;   // FF phase: [512][2048] = 4 slots (4..7)

  const dim3 tpb(32, 8);
  const dim3 gQKV(12, 256);    // N=1536 fused, 3072 blocks (%8==0)
  const dim3 gProj(4, 256);    // 1024 blocks
  const dim3 gAttn(512, 8);

  // ---- prologue: both LNs in one pass (x read once) ----
  ln_k<1><<<8192, 256, 0, stream>>>(x, rg, rb, cg, cb, A0, D0);

  // ---- row branch ----
  tranb3<<<dim3(16, 16, 3), tpb, 0, stream>>>(row_qw, row_kw, row_vw, wt_q, wt_k, wt_v);
  tranbP<<<dim3(16, 16), tpb, 0, stream>>>(row_pw, wt_p, 0);
  gemm128<0, true><<<gQKV, 512, 0, stream>>>(A0, A0, 99, wt_q, row_qb, row_kb, row_vb,
                                             nullptr, A1, A2, A3, 512, 512, 512);
  attn64<<<gAttn, 256, 0, stream>>>(A1, A2, A3, rrel, 1, 64);     // rowO -> A1

  // ---- col branch ----
  tranb3<<<dim3(16, 16, 3), tpb, 0, stream>>>(col_qw, col_kw, col_vw, wt_q, wt_k, wt_v);
  tranbP<<<dim3(16, 16), tpb, 0, stream>>>(col_pw, wt_p, 512);
  gemm128<0, true><<<gQKV, 512, 0, stream>>>(D0, D0, 99, wt_q, col_qb, col_kb, col_vb,
                                             nullptr, A2, A3, D1, 512, 512, 512);
  attn64<<<gAttn, 256, 0, stream>>>(A2, A3, D1, crel, 64, 1);     // colO -> A2

  // ---- fused projection: out = x + rowO@rowPw + colO@colPw (K=1024) ----
  gemm128<2, false><<<gProj, 512, 0, stream>>>(A1, A2, 8, wt_p, row_pb, col_pb,
                                               nullptr, x, outp, nullptr, nullptr,
                                               512, 1024, 512);

  // ---- FFN (2 chunks of 16384 rows; hid = A1..A2) ----
  ln_k<0><<<8192, 256, 0, stream>>>(outp, l2g, l2b, nullptr, nullptr, A0, nullptr);
  tranb<<<dim3(64, 16), tpb, 0, stream>>>(ffw1, f1t, 512, 2048);   // [2048][512]
  tranb<<<dim3(16, 64), tpb, 0, stream>>>(ffw2, f2t, 2048, 512);   // [512][2048]
  for (int c = 0; c < 2; ++c){
    const size_t ro = (size_t)c * 16384;
    gemm128<1, false><<<dim3(16, 128), 512, 0, stream>>>(A0 + ro * 512, A0, 99, f1t,
        ffb1, nullptr, nullptr, nullptr, A1, nullptr, nullptr, 2048, 512, 512);
    gemm128<2, false><<<dim3(4, 128), 512, 0, stream>>>(A1, A1, 99, f2t,
        ffb2, nullptr, nullptr, outp + ro * 512, outp + ro * 512, nullptr, nullptr,
        512, 2048, 2048);
  }
}

// Round 16
// 465.270 us; speedup vs baseline: 1.3749x; 1.0144x over previous
//
#include <hip/hip_runtime.h>

typedef unsigned short u16;
typedef unsigned int   u32;
typedef float  f32x4  __attribute__((ext_vector_type(4)));
typedef u32    u32x4  __attribute__((ext_vector_type(4)));
typedef __bf16 bf16x8 __attribute__((ext_vector_type(8)));

#define DEV __device__ __forceinline__

DEV float b2f(u16 u){ return __uint_as_float(((u32)u) << 16); }
DEV u16 f2b(float f){
  u32 u = __float_as_uint(f);
  u32 r = 0x7FFFu + ((u >> 16) & 1u);
  return (u16)((u + r) >> 16);
}
DEV u32 pack2(float a, float b){ return (u32)f2b(a) | ((u32)f2b(b) << 16); }
DEV uint4 pack8(const float* o){
  uint4 r;
  r.x = pack2(o[0], o[1]); r.y = pack2(o[2], o[3]);
  r.z = pack2(o[4], o[5]); r.w = pack2(o[6], o[7]);
  return r;
}
DEV void unpack8b(uint4 v, float* f){
  u32 w;
  w = v.x; f[0] = b2f((u16)w); f[1] = b2f((u16)(w >> 16));
  w = v.y; f[2] = b2f((u16)w); f[3] = b2f((u16)(w >> 16));
  w = v.z; f[4] = b2f((u16)w); f[5] = b2f((u16)(w >> 16));
  w = v.w; f[6] = b2f((u16)w); f[7] = b2f((u16)(w >> 16));
}

// D = A(16x32)*B(32x16)+C. A/B frag: lane holds 8 contiguous k
// (k = 8*(lane>>4)+e) of row/col (lane&15). C/D: col=lane&15,
// row=4*(lane>>4)+reg  [m89/m91-verified].
DEV f32x4 mfma16(u32x4 a, u32x4 b, f32x4 c){
  return __builtin_amdgcn_mfma_f32_16x16x32_bf16(
      __builtin_bit_cast(bf16x8, a), __builtin_bit_cast(bf16x8, b), c, 0, 0, 0);
}

DEV void gload16(const u16* g, u16* l){
  __builtin_amdgcn_global_load_lds((const __attribute__((address_space(1))) void*)(g),
                                   (__attribute__((address_space(3))) void*)(l), 16, 0, 0);
}

// ---------------------------------------------------------------- transposes
// 3 x [512][512] f32 -> bf16 transposed (QKV weights), batched via blockIdx.z
__global__ __launch_bounds__(256) void tranb3(
    const float* __restrict__ sA, const float* __restrict__ sB,
    const float* __restrict__ sC,
    u16* __restrict__ dA, u16* __restrict__ dB, u16* __restrict__ dC){
  __shared__ float tile[32][33];
  const float* src = (blockIdx.z == 0) ? sA : (blockIdx.z == 1) ? sB : sC;
  u16* dst = (blockIdx.z == 0) ? dA : (blockIdx.z == 1) ? dB : dC;
  const int bx = blockIdx.x * 32, by = blockIdx.y * 32;
  const int tx = threadIdx.x, ty = threadIdx.y;
#pragma unroll
  for (int i = 0; i < 4; ++i)
    tile[ty + i * 8][tx] = src[(size_t)(by + ty + i * 8) * 512 + bx + tx];
  __syncthreads();
#pragma unroll
  for (int i = 0; i < 4; ++i)
    dst[(size_t)(bx + ty + i * 8) * 512 + by + tx] = f2b(tile[tx][ty + i * 8]);
}

// [512][512] f32 -> dst[c*1024 + off + r] (fused projT, ld=1024, col offset)
__global__ __launch_bounds__(256) void tranbP(const float* __restrict__ src,
                                              u16* __restrict__ dst, int off){
  __shared__ float tile[32][33];
  const int bx = blockIdx.x * 32, by = blockIdx.y * 32;
  const int tx = threadIdx.x, ty = threadIdx.y;
#pragma unroll
  for (int i = 0; i < 4; ++i)
    tile[ty + i * 8][tx] = src[(size_t)(by + ty + i * 8) * 512 + bx + tx];
  __syncthreads();
#pragma unroll
  for (int i = 0; i < 4; ++i)
    dst[(size_t)(bx + ty + i * 8) * 1024 + off + by + tx] = f2b(tile[tx][ty + i * 8]);
}

// src [R][C] f32 -> dst [C][R] bf16 (FFN weights)
__global__ __launch_bounds__(256) void tranb(const float* __restrict__ src, u16* __restrict__ dst,
                                             int R, int C){
  __shared__ float tile[32][33];
  const int bx = blockIdx.x * 32, by = blockIdx.y * 32;
  const int tx = threadIdx.x, ty = threadIdx.y;
#pragma unroll
  for (int i = 0; i < 4; ++i)
    tile[ty + i * 8][tx] = src[(size_t)(by + ty + i * 8) * C + bx + tx];
  __syncthreads();
#pragma unroll
  for (int i = 0; i < 4; ++i)
    dst[(size_t)(bx + ty + i * 8) * R + by + tx] = f2b(tile[tx][ty + i * 8]);
}

// ---------------------------------------------------------------- layernorm
// One wave per 512-elem row. BF16IN: input is bf16 (else f32). bf16 out.
// TWO=1: two gamma/beta sets.
template<int TWO, int BF16IN>
__global__ __launch_bounds__(256) void ln_k(const void* __restrict__ xv,
    const float* __restrict__ g1, const float* __restrict__ b1,
    const float* __restrict__ g2, const float* __restrict__ b2,
    u16* __restrict__ y1, u16* __restrict__ y2){
  const int tid = threadIdx.x, lane = tid & 63, wv = tid >> 6;
  const size_t row  = (size_t)blockIdx.x * 4 + wv;
  const size_t boff = row * 512 + lane * 8;
  float f[8];
  if (BF16IN){
    unpack8b(*(const uint4*)((const u16*)xv + boff), f);
  } else {
    const f32x4* p = (const f32x4*)((const float*)xv + boff);
    const f32x4 a = p[0], b = p[1];
#pragma unroll
    for (int j = 0; j < 4; ++j){ f[j] = a[j]; f[4 + j] = b[j]; }
  }
  float s1 = 0.f, s2 = 0.f;
#pragma unroll
  for (int j = 0; j < 8; ++j){ s1 += f[j]; s2 += f[j] * f[j]; }
#pragma unroll
  for (int off = 32; off > 0; off >>= 1){
    s1 += __shfl_xor(s1, off);
    s2 += __shfl_xor(s2, off);
  }
  const float m   = s1 * (1.0f / 512.0f);
  const float var = s2 * (1.0f / 512.0f) - m * m;
  const float inv = rsqrtf(var + 1e-4f);
  const int cb = lane * 8;
  float o[8];
#pragma unroll
  for (int j = 0; j < 8; ++j) o[j] = (f[j] - m) * inv * g1[cb + j] + b1[cb + j];
  *(uint4*)(y1 + boff) = pack8(o);
  if (TWO){
#pragma unroll
    for (int j = 0; j < 8; ++j) o[j] = (f[j] - m) * inv * g2[cb + j] + b2[cb + j];
    *(uint4*)(y2 + boff) = pack8(o);
  }
}

// ---------------------------------------------------------------- GEMM
// out = [A | A2nd](M x K, switch at K-tile nkA) @ Bt[N][K]^T + bias
// EPI 0: bf16 | 1: bf16+gelu | 2: f32 out + f32 res | 3: bf16 out + f32 res
//     | 4: f32 out + bf16 res.  (2/3/4 support optional 2nd bias b1p.)
// FUSE3: segmented bias per 512 cols AND split output buffers per 512 cols.
// 128x128 tile, BK=64, 512 thr = 8 waves (2Mx4N, 64x32 each), 64KB LDS
// double-buffered -> 2 blocks/CU. T4 counted vmcnt(4), T2 XOR-8 swizzle
// (pre-swizzled global source, swizzled read), T5 setprio, T1 XCD swizzle.
// [Session optimum structure: r9/r10 measured 472-474 us; all geometry
//  departures (256^2 1-blk/CU, BK=32, 4-wave 64x64, deep pipeline) regressed.]
template<int EPI, bool FUSE3>
__global__ __launch_bounds__(512, 2) void gemm128(const u16* __restrict__ A,
    const u16* __restrict__ A2nd, int nkA,
    const u16* __restrict__ Bt,
    const float* __restrict__ b0p, const float* __restrict__ b1p,
    const float* __restrict__ b2p,
    const float* __restrict__ res,
    void* __restrict__ out0, void* __restrict__ out1, void* __restrict__ out2,
    int Nd, int K, int lda){
  __shared__ __align__(16) u16 smem[32768];       // 64 KB, reused by epilogue
  const int tid  = threadIdx.x;
  const int lane = tid & 63;
  const int lr = lane & 15, lg = lane >> 4;
  const int wave = tid >> 6;
  const int wm = (wave >> 2) * 64, wn = (wave & 3) * 32;
  // T1: bijective XCD swizzle (all grids have nwg % 8 == 0)
  const u32 fd  = blockIdx.y * gridDim.x + blockIdx.x;
  const u32 cpx = (gridDim.x * gridDim.y) >> 3;
  const u32 T   = (fd & 7) * cpx + (fd >> 3);
  const int m0 = (T / gridDim.x) * 128, n0 = (T % gridDim.x) * 128;
  const int nk = K >> 6;

  f32x4 acc[4][2] = {};

  // LDS chunk (r, s) holds global chunk (r, s^(r&7)); reader inverts.
  auto stage = [&](int buf, int kt){
    const u16* Ap; int kb;
    if (kt < nkA){ Ap = A;    kb = kt * 64; }
    else         { Ap = A2nd; kb = (kt - nkA) * 64; }
    const int kbB = kt * 64;
    const int ao = buf * 8192, bo = 16384 + buf * 8192;
#pragma unroll
    for (int i = 0; i < 2; ++i){
      const int c = i * 512 + tid;
      const int r = c >> 3, gc = (c & 7) ^ (r & 7);
      gload16(Ap + (size_t)(m0 + r) * lda + kb + gc * 8, smem + ao + c * 8);
    }
#pragma unroll
    for (int i = 0; i < 2; ++i){
      const int c = i * 512 + tid;
      const int r = c >> 3, gc = (c & 7) ^ (r & 7);
      gload16(Bt + (size_t)(n0 + r) * K + kbB + gc * 8, smem + bo + c * 8);
    }
  };

  stage(0, 0);
  int cur = 0;
  for (int kt = 0; kt < nk; ++kt){
    if (kt + 1 < nk){
      stage(cur ^ 1, kt + 1);                          // issue next FIRST
      asm volatile("s_waitcnt vmcnt(4)" ::: "memory"); // tile kt done, kt+1 in flight
    } else {
      asm volatile("s_waitcnt vmcnt(0)" ::: "memory");
    }
    __builtin_amdgcn_s_barrier();
    __builtin_amdgcn_sched_barrier(0);
    const int ao = cur * 8192, bo = 16384 + cur * 8192;
#pragma unroll
    for (int kk = 0; kk < 2; ++kk){
      u32x4 af[4], bf[2];
#pragma unroll
      for (int t = 0; t < 4; ++t){
        const int js = (kk * 4 + lg) ^ (lr & 7);       // unswizzle chunk
        af[t] = *(const u32x4*)&smem[ao + (wm + t * 16 + lr) * 64 + js * 8];
      }
#pragma unroll
      for (int t = 0; t < 2; ++t){
        const int js = (kk * 4 + lg) ^ (lr & 7);
        bf[t] = *(const u32x4*)&smem[bo + (wn + t * 16 + lr) * 64 + js * 8];
      }
      __builtin_amdgcn_s_setprio(1);
#pragma unroll
      for (int mt = 0; mt < 4; ++mt)
#pragma unroll
        for (int nt = 0; nt < 2; ++nt)
          acc[mt][nt] = mfma16(af[mt], bf[nt], acc[mt][nt]);
      __builtin_amdgcn_s_setprio(0);
    }
    asm volatile("" ::: "memory");                     // no LDS-read sinking
    __builtin_amdgcn_sched_barrier(0);
    __builtin_amdgcn_s_barrier();
    cur ^= 1;
  }

  if (EPI >= 2){
    // residual paths: stage 128x128 f32 tile (64 KB), coalesced write phase
    float* Cf = (float*)smem;
#pragma unroll
    for (int mt = 0; mt < 4; ++mt)
#pragma unroll
      for (int nt = 0; nt < 2; ++nt){
        const int col = wn + nt * 16 + lr;
        float bv = b0p ? b0p[n0 + col] : 0.0f;
        if (b1p) bv += b1p[n0 + col];
#pragma unroll
        for (int r = 0; r < 4; ++r)
          Cf[(wm + mt * 16 + lg * 4 + r) * 128 + col] = acc[mt][nt][r] + bv;
      }
    __syncthreads();
#pragma unroll
    for (int p = 0; p < 8; ++p){
      const int rr = p * 16 + (tid >> 5);
      const int cc = (tid & 31) * 4;
      f32x4 c = *(f32x4*)&Cf[rr * 128 + cc];
      const size_t gi = (size_t)(m0 + rr) * Nd + n0 + cc;
      if (EPI == 4){
        const u16* rb16 = (const u16*)res;             // bf16 residual
        const uint2 rv = *(const uint2*)(rb16 + gi);
        c[0] += b2f((u16)rv.x); c[1] += b2f((u16)(rv.x >> 16));
        c[2] += b2f((u16)rv.y); c[3] += b2f((u16)(rv.y >> 16));
      } else {
        c += *(const f32x4*)(res + gi);
      }
      if (EPI == 3){
        u16* o16 = (u16*)out0;                         // bf16 out (mid)
        uint2 ov; ov.x = pack2(c[0], c[1]); ov.y = pack2(c[2], c[3]);
        *(uint2*)(o16 + gi) = ov;
      } else {
        *(f32x4*)((float*)out0 + gi) = c;
      }
    }
  } else {
    // bf16 path: stage 128x(128+8) u16 tile
    u16* Cl = smem;
#pragma unroll
    for (int mt = 0; mt < 4; ++mt)
#pragma unroll
      for (int nt = 0; nt < 2; ++nt){
        const int col = n0 + wn + nt * 16 + lr;
        float bv;
        if (FUSE3){
          if (col >= 1024)      bv = b2p[col - 1024];
          else if (col >= 512)  bv = b1p[col - 512];
          else                  bv = b0p[col];
        } else bv = b0p[col];
#pragma unroll
        for (int r = 0; r < 4; ++r){
          float v2 = acc[mt][nt][r] + bv;
          if (EPI == 1) v2 = 0.5f * v2 * (1.0f + erff(v2 * 0.70710678118654752f));
          Cl[(wm + mt * 16 + lg * 4 + r) * 136 + wn + nt * 16 + lr] = f2b(v2);
        }
      }
    __syncthreads();
    u16* o = (u16*)out0;
    int ncol = n0;
    if (FUSE3){
      const int grp = n0 >> 9;
      o = (u16*)(grp == 0 ? out0 : grp == 1 ? out1 : out2);
      ncol = n0 & 511;
    }
#pragma unroll
    for (int p = 0; p < 4; ++p){
      const int rr = p * 32 + (tid >> 4);
      const int cc = (tid & 15) * 8;
      *(uint4*)(o + (size_t)(m0 + rr) * (FUSE3 ? 512 : Nd) + ncol + cc) =
          *(uint4*)&Cl[rr * 136 + cc];
    }
  }
}

// ---------------------------------------------------------------- attention
// One block per (sequence, head). T=64, hd=64, 4 waves. Separate q/k/v
// buffers (row stride 512). Writes output IN-PLACE over q (block reads its
// own (s,head) slice into LDS first; slices disjoint across blocks).
// Token t -> row base + t*tstr, base = (s>>6)*4096 + (s&63)*sscale.
__global__ __launch_bounds__(256, 2) void attn64(u16* __restrict__ q,
    const u16* __restrict__ k, const u16* __restrict__ v,
    const float* __restrict__ relw,
    int sscale, int tstr){
  __shared__ __align__(16) u16 Qs[64 * 80];
  __shared__ __align__(16) u16 Ks[64 * 80];
  __shared__ __align__(16) u16 Vt[64 * 80];   // V transposed: Vt[d][t]
  __shared__ __align__(16) u16 Ps[64 * 80];
  __shared__ float Ss[64 * 68];
  __shared__ float tb[128];

  const int s = blockIdx.x, head = blockIdx.y;
  const int tid = threadIdx.x;
  const int lane = tid & 63, wv = tid >> 6;
  const int lr = lane & 15, lg = lane >> 4;
  const int base = (s >> 6) * 4096 + (s & 63) * sscale;

  if (tid < 127) tb[tid] = relw[tid * 8 + head];

#pragma unroll
  for (int rep = 0; rep < 2; ++rep){
    const int e = rep * 2048 + tid * 8;
    const int t = e >> 6, c = e & 63;
    const size_t goff = (size_t)(base + t * tstr) * 512 + head * 64 + c;
    *(uint4*)&Qs[t * 80 + c] = *(const uint4*)(q + goff);
    *(uint4*)&Ks[t * 80 + c] = *(const uint4*)(k + goff);
    const uint4 vvv = *(const uint4*)(v + goff);
    u32 w;
    w = vvv.x; Vt[(c + 0) * 80 + t] = (u16)w; Vt[(c + 1) * 80 + t] = (u16)(w >> 16);
    w = vvv.y; Vt[(c + 2) * 80 + t] = (u16)w; Vt[(c + 3) * 80 + t] = (u16)(w >> 16);
    w = vvv.z; Vt[(c + 4) * 80 + t] = (u16)w; Vt[(c + 5) * 80 + t] = (u16)(w >> 16);
    w = vvv.w; Vt[(c + 6) * 80 + t] = (u16)w; Vt[(c + 7) * 80 + t] = (u16)(w >> 16);
  }
  __syncthreads();

  const int i0 = wv * 16;
  // S = Q K^T * 0.125 + rel
  u32x4 af[2];
#pragma unroll
  for (int kk = 0; kk < 2; ++kk)
    af[kk] = *(const u32x4*)&Qs[(i0 + lr) * 80 + kk * 32 + lg * 8];
#pragma unroll
  for (int jt = 0; jt < 4; ++jt){
    f32x4 acc = {};
#pragma unroll
    for (int kk = 0; kk < 2; ++kk){
      const u32x4 bf = *(const u32x4*)&Ks[(jt * 16 + lr) * 80 + kk * 32 + lg * 8];
      acc = mfma16(af[kk], bf, acc);
    }
#pragma unroll
    for (int r = 0; r < 4; ++r){
      const int i = i0 + lg * 4 + r;
      const int j = jt * 16 + lr;
      Ss[i * 68 + j] = acc[r] * 0.125f + tb[j - i + 63];
    }
  }
  __syncthreads();

  // softmax: 4 lanes per row
  {
    const int rr = tid >> 2, cp = tid & 3;
    float ev[16];
    float mx = -3.0e38f;
#pragma unroll
    for (int u = 0; u < 16; ++u){ ev[u] = Ss[rr * 68 + cp * 16 + u]; mx = fmaxf(mx, ev[u]); }
    mx = fmaxf(mx, __shfl_xor(mx, 1, 4));
    mx = fmaxf(mx, __shfl_xor(mx, 2, 4));
    float sum = 0.f;
#pragma unroll
    for (int u = 0; u < 16; ++u){ ev[u] = expf(ev[u] - mx); sum += ev[u]; }
    sum += __shfl_xor(sum, 1, 4);
    sum += __shfl_xor(sum, 2, 4);
    const float inv = 1.0f / sum;
#pragma unroll
    for (int u = 0; u < 16; ++u) Ps[rr * 80 + cp * 16 + u] = f2b(ev[u] * inv);
  }
  __syncthreads();

  // O = P V -> stage into Qs
  u32x4 pa[2];
#pragma unroll
  for (int kk = 0; kk < 2; ++kk)
    pa[kk] = *(const u32x4*)&Ps[(i0 + lr) * 80 + kk * 32 + lg * 8];
#pragma unroll
  for (int dt = 0; dt < 4; ++dt){
    f32x4 acc = {};
#pragma unroll
    for (int kk = 0; kk < 2; ++kk){
      const u32x4 bf = *(const u32x4*)&Vt[(dt * 16 + lr) * 80 + kk * 32 + lg * 8];
      acc = mfma16(pa[kk], bf, acc);
    }
#pragma unroll
    for (int r = 0; r < 4; ++r)
      Qs[(i0 + lg * 4 + r) * 80 + dt * 16 + lr] = f2b(acc[r]);
  }
  __syncthreads();

  // coalesced out-write: 128 B per row (whole head slice), over q
#pragma unroll
  for (int p = 0; p < 2; ++p){
    const int rr = p * 32 + (tid >> 3);
    const int cc = (tid & 7) * 8;
    *(uint4*)(q + (size_t)(base + rr * tstr) * 512 + head * 64 + cc) =
        *(uint4*)&Qs[rr * 80 + cc];
  }
}

// ---------------------------------------------------------------- launcher
extern "C" void kernel_launch(void* const* d_in, const int* in_sizes, int n_in,
                              void* d_out, int out_size, void* d_ws, size_t ws_size,
                              hipStream_t stream){
  const float* x      = (const float*)d_in[0];
  const float* row_qw = (const float*)d_in[1];  const float* row_qb = (const float*)d_in[2];
  const float* row_kw = (const float*)d_in[3];  const float* row_kb = (const float*)d_in[4];
  const float* row_vw = (const float*)d_in[5];  const float* row_vb = (const float*)d_in[6];
  const float* row_pw = (const float*)d_in[7];  const float* row_pb = (const float*)d_in[8];
  const float* col_qw = (const float*)d_in[9];  const float* col_qb = (const float*)d_in[10];
  const float* col_kw = (const float*)d_in[11]; const float* col_kb = (const float*)d_in[12];
  const float* col_vw = (const float*)d_in[13]; const float* col_vb = (const float*)d_in[14];
  const float* col_pw = (const float*)d_in[15]; const float* col_pb = (const float*)d_in[16];
  const float* rg  = (const float*)d_in[17]; const float* rb  = (const float*)d_in[18];
  const float* cg  = (const float*)d_in[19]; const float* cb  = (const float*)d_in[20];
  const float* l2g = (const float*)d_in[21]; const float* l2b = (const float*)d_in[22];
  const float* ffw1 = (const float*)d_in[23]; const float* ffb1 = (const float*)d_in[24];
  const float* ffw2 = (const float*)d_in[25]; const float* ffb2 = (const float*)d_in[26];
  const float* rrel = (const float*)d_in[27]; const float* crel = (const float*)d_in[28];
  float* outp = (float*)d_out;
  u16* outp16 = (u16*)d_out;

  const size_t ACT = (size_t)32768 * 512;          // activation buffer (elems)
  const size_t W55 = (size_t)512 * 512;
  const size_t NEED = (4 * ACT + 8 * W55) * 2;     // bytes = 138,412,032
  if (ws_size < NEED) return;                      // sentinel: d_out stays 0

  u16* A0 = (u16*)d_ws;        // rowLN / ln2 out
  u16* A1 = A0 + ACT;          // rowQ -> rowO ; FFN hid (A1..A2)
  u16* A2 = A1 + ACT;          // rowK ; colQ -> colO ; FFN hid
  u16* A3 = A2 + ACT;          // rowV ; colK ; mid (bf16) after proj
  u16* D0 = outp16;            // colLN (bf16 scratch in d_out, dies at proj)
  u16* D1 = outp16 + ACT;      // colV  (bf16 scratch in d_out, dies at proj)
  u16* wtb = A3 + ACT;         // weight area: 8 x W55
  u16* wt_q = wtb;  u16* wt_k = wtb + W55;  u16* wt_v = wtb + 2 * W55;
  u16* wt_p = wtb + 3 * W55;   // fused projT [512][1024] = 2 slots (3..4)
  u16* f1t  = wtb;             // FF phase: [2048][512] = 4 slots (0..3)
  u16* f2t  = wtb + 4 * W55;   // FF phase: [512][2048] = 4 slots (4..7)

  const dim3 tpb(32, 8);
  const dim3 gQKV(12, 256);    // N=1536 fused, 3072 blocks (%8==0)
  const dim3 gProj(4, 256);    // 1024 blocks
  const dim3 gAttn(512, 8);

  // ---- prologue: both LNs in one pass (x read once) ----
  ln_k<1, 0><<<8192, 256, 0, stream>>>(x, rg, rb, cg, cb, A0, D0);

  // ---- row branch ----
  tranb3<<<dim3(16, 16, 3), tpb, 0, stream>>>(row_qw, row_kw, row_vw, wt_q, wt_k, wt_v);
  tranbP<<<dim3(16, 16), tpb, 0, stream>>>(row_pw, wt_p, 0);
  gemm128<0, true><<<gQKV, 512, 0, stream>>>(A0, A0, 99, wt_q, row_qb, row_kb, row_vb,
                                             nullptr, A1, A2, A3, 512, 512, 512);
  attn64<<<gAttn, 256, 0, stream>>>(A1, A2, A3, rrel, 1, 64);     // rowO -> A1

  // ---- col branch ----
  tranb3<<<dim3(16, 16, 3), tpb, 0, stream>>>(col_qw, col_kw, col_vw, wt_q, wt_k, wt_v);
  tranbP<<<dim3(16, 16), tpb, 0, stream>>>(col_pw, wt_p, 512);
  gemm128<0, true><<<gQKV, 512, 0, stream>>>(D0, D0, 99, wt_q, col_qb, col_kb, col_vb,
                                             nullptr, A2, A3, D1, 512, 512, 512);
  attn64<<<gAttn, 256, 0, stream>>>(A2, A3, D1, crel, 64, 1);     // colO -> A2

  // ---- fused projection: mid(bf16) = x + rowO@rowPw + colO@colPw (K=1024) ----
  gemm128<3, false><<<gProj, 512, 0, stream>>>(A1, A2, 8, wt_p, row_pb, col_pb,
                                               nullptr, x, A3, nullptr, nullptr,
                                               512, 1024, 512);

  // ---- FFN (2 chunks of 16384 rows; hid = A1..A2; final f32 out by FF2) ----
  ln_k<0, 1><<<8192, 256, 0, stream>>>(A3, l2g, l2b, nullptr, nullptr, A0, nullptr);
  tranb<<<dim3(64, 16), tpb, 0, stream>>>(ffw1, f1t, 512, 2048);   // [2048][512]
  tranb<<<dim3(16, 64), tpb, 0, stream>>>(ffw2, f2t, 2048, 512);   // [512][2048]
  for (int c = 0; c < 2; ++c){
    const size_t ro = (size_t)c * 16384;
    gemm128<1, false><<<dim3(16, 128), 512, 0, stream>>>(A0 + ro * 512, A0, 99, f1t,
        ffb1, nullptr, nullptr, nullptr, A1, nullptr, nullptr, 2048, 512, 512);
    gemm128<4, false><<<dim3(4, 128), 512, 0, stream>>>(A1, A1, 99, f2t,
        ffb2, nullptr, nullptr, (const float*)(A3 + ro * 512),
        outp + ro * 512, nullptr, nullptr, 512, 2048, 2048);
  }
}